// Round 1
// 295.323 us; speedup vs baseline: 1.2043x; 1.2043x over previous
//
#include <hip/hip_runtime.h>
#include <hip/hip_bf16.h>
#include <math.h>

#define NV   5023
#define N3   15069
#define NB   2048
#define NTIL 79            // ceil(N3/192) column tiles
#define NPAD (NTIL*192)    // 15168 padded B rows

// ---- workspace byte offsets ----
#define WS_JD_B   0          // 2272 floats
#define WS_ATR_B  9216       // 2048*60*4  = 491520
#define WS_PF_B   500736     // 2048*36*4  = 294912 (fp32 pose_feature)
#define WS_AB_B   795648     // 2048*192*2 = 786432 (bf16 A)
#define WS_BB_B   1582080    // 15168*192*2 = 5824512 (bf16 B, n-major, padded)

typedef __attribute__((ext_vector_type(8))) short short8;
typedef __attribute__((ext_vector_type(4))) float floatx4;

// ---------------- zero the Jdirs accumulator region ----------------
__global__ void k_zero(char* ws) {
    int i = blockIdx.x * 256 + threadIdx.x;
    if (i < 2272) ((float*)(ws + WS_JD_B))[i] = 0.f;
}

// ---------------- Jdirs: 126 slices x 40 verts ----------------
__global__ void k_jdirs(const float* __restrict__ Jreg,   // [5][NV]
                        const float* __restrict__ sdirs,  // [NV][450]
                        const float* __restrict__ vt,     // [NV][3]
                        char* __restrict__ ws) {
    int slice = blockIdx.x;        // 0..125
    int start = slice * 40;
    int end   = min(start + 40, NV);
    int t = threadIdx.x;
    int s0 = t, s1 = t + 256;
    float a0[5] = {0,0,0,0,0}, a1[5] = {0,0,0,0,0};
    for (int v = start; v < end; ++v) {
        float w[5];
        #pragma unroll
        for (int j = 0; j < 5; ++j) w[j] = Jreg[j * NV + v];
        float x0 = (s0 < 450) ? sdirs[(size_t)v * 450 + s0]
                 : (s0 < 453 ? vt[v * 3 + (s0 - 450)] : 0.f);
        float x1 = (s1 < 450) ? sdirs[(size_t)v * 450 + s1]
                 : (s1 < 453 ? vt[v * 3 + (s1 - 450)] : 0.f);
        #pragma unroll
        for (int j = 0; j < 5; ++j) { a0[j] += w[j] * x0; a1[j] += w[j] * x1; }
    }
    float* Jd = (float*)(ws + WS_JD_B);
    #pragma unroll
    for (int j = 0; j < 5; ++j) {
        if (s0 < 453) atomicAdd(&Jd[j * 453 + s0], a0[j]);
        if (s1 < 453) atomicAdd(&Jd[j * 453 + s1], a1[j]);
    }
}

// ---------------- per-batch: J GEMV, rodrigues, chain -> pf (fp32), Atr ----------------
__global__ void k_batch(const float* __restrict__ shp,
                        const float* __restrict__ expn,
                        const float* __restrict__ neck,
                        const float* __restrict__ jaw,
                        const float* __restrict__ eye,
                        char* __restrict__ ws) {
    __shared__ float JdL[2265];
    {
        const float* Jd = (const float*)(ws + WS_JD_B);
        for (int i = threadIdx.x; i < 2265; i += 256) JdL[i] = Jd[i];
    }
    __syncthreads();
    int b = blockIdx.x * 256 + threadIdx.x;
    float* pf  = (float*)(ws + WS_PF_B) + (size_t)b * 36;
    float* Atr = (float*)(ws + WS_ATR_B) + (size_t)b * 60;

    float J[15];
    for (int jk = 0; jk < 15; ++jk) J[jk] = JdL[(jk / 3) * 453 + 450 + (jk % 3)];
    for (int l = 0; l < 150; ++l) {
        float be = (l < 100) ? shp[(size_t)b * 100 + l] : expn[(size_t)b * 50 + (l - 100)];
        #pragma unroll
        for (int jj = 0; jj < 5; ++jj)
            #pragma unroll
            for (int kk = 0; kk < 3; ++kk)
                J[jj * 3 + kk] += JdL[jj * 453 + kk * 150 + l] * be;
    }

    float R[5][9];
    for (int jj = 0; jj < 5; ++jj) {
        float rx, ry, rz;
        if (jj == 0)      { rx = 0.f; ry = 0.f; rz = 0.f; }
        else if (jj == 1) { rx = neck[b*3]; ry = neck[b*3+1]; rz = neck[b*3+2]; }
        else if (jj == 2) { rx = jaw[b*3];  ry = jaw[b*3+1];  rz = jaw[b*3+2];  }
        else if (jj == 3) { rx = eye[b*6];  ry = eye[b*6+1];  rz = eye[b*6+2];  }
        else              { rx = eye[b*6+3]; ry = eye[b*6+4]; rz = eye[b*6+5];  }
        float ax = rx + 1e-8f, ay = ry + 1e-8f, az = rz + 1e-8f;
        float angle = sqrtf(ax*ax + ay*ay + az*az);
        float inv = 1.f / angle;
        float ux = rx * inv, uy = ry * inv, uz = rz * inv;
        float c = cosf(angle), s = sinf(angle);
        float K[9] = {0.f, -uz, uy,  uz, 0.f, -ux,  -uy, ux, 0.f};
        float KK[9];
        #pragma unroll
        for (int r = 0; r < 3; ++r)
            #pragma unroll
            for (int cc = 0; cc < 3; ++cc) {
                float a = 0.f;
                #pragma unroll
                for (int m = 0; m < 3; ++m) a += K[r*3+m] * K[m*3+cc];
                KK[r*3+cc] = a;
            }
        #pragma unroll
        for (int e = 0; e < 9; ++e) R[jj][e] = s * K[e] + (1.f - c) * KK[e];
        R[jj][0] += 1.f; R[jj][4] += 1.f; R[jj][8] += 1.f;
    }

    for (int jj = 1; jj < 5; ++jj)
        #pragma unroll
        for (int e = 0; e < 9; ++e)
            pf[(jj-1)*9 + e] = R[jj][e] - ((e == 0 || e == 4 || e == 8) ? 1.f : 0.f);

    float G[5][12];
    #pragma unroll
    for (int r = 0; r < 3; ++r) {
        #pragma unroll
        for (int cc = 0; cc < 3; ++cc) G[0][r*4+cc] = R[0][r*3+cc];
        G[0][r*4+3] = J[r];
    }
    const int par[5] = {-1, 0, 1, 1, 1};
    for (int jj = 1; jj < 5; ++jj) {
        int p = par[jj];
        float rel[3];
        #pragma unroll
        for (int r = 0; r < 3; ++r) rel[r] = J[jj*3+r] - J[p*3+r];
        #pragma unroll
        for (int r = 0; r < 3; ++r) {
            #pragma unroll
            for (int cc = 0; cc < 3; ++cc) {
                float a = 0.f;
                #pragma unroll
                for (int m = 0; m < 3; ++m) a += G[p][r*4+m] * R[jj][m*3+cc];
                G[jj][r*4+cc] = a;
            }
            float tt = G[p][r*4+3];
            #pragma unroll
            for (int m = 0; m < 3; ++m) tt += G[p][r*4+m] * rel[m];
            G[jj][r*4+3] = tt;
        }
    }
    for (int jj = 0; jj < 5; ++jj)
        #pragma unroll
        for (int r = 0; r < 3; ++r) {
            float tc = 0.f;
            #pragma unroll
            for (int m = 0; m < 3; ++m) tc += G[jj][r*4+m] * J[jj*3+m];
            Atr[jj*12 + r*4 + 0] = G[jj][r*4+0];
            Atr[jj*12 + r*4 + 1] = G[jj][r*4+1];
            Atr[jj*12 + r*4 + 2] = G[jj][r*4+2];
            Atr[jj*12 + r*4 + 3] = G[jj][r*4+3] - tc;
        }
}

// ---------------- build bf16 A [2048][192], fully coalesced ----------------
__global__ void k_aconv(const float* __restrict__ shp,
                        const float* __restrict__ expn,
                        char* __restrict__ ws) {
    int idx = blockIdx.x * 256 + threadIdx.x;   // < 2048*192
    int b = idx / 192, k = idx % 192;
    float v;
    if (k < 100)      v = shp[(size_t)b * 100 + k];
    else if (k < 150) v = expn[(size_t)b * 50 + (k - 100)];
    else if (k < 186) v = ((const float*)(ws + WS_PF_B))[(size_t)b * 36 + (k - 150)];
    else              v = 0.f;
    ((__hip_bfloat16*)(ws + WS_AB_B))[idx] = __float2bfloat16(v);
}

// ---------------- build bf16 B [NPAD][192]: coalesced 16B writes ----------------
__global__ void k_bconv(const float* __restrict__ sdirs,  // [N3][150]
                        const float* __restrict__ pdirs,  // [36][N3]
                        char* __restrict__ ws) {
    int idx = blockIdx.x * 256 + threadIdx.x;   // < NPAD*24
    int kg = idx % 24, n = idx / 24;
    int k0 = kg * 8;
    __hip_bfloat16 val[8];
    #pragma unroll
    for (int e = 0; e < 8; ++e) {
        int k = k0 + e;
        float v = 0.f;
        if (n < N3) {
            if (k < 150)      v = sdirs[(size_t)n * 150 + k];
            else if (k < 186) v = pdirs[(size_t)(k - 150) * N3 + n];
        }
        val[e] = __float2bfloat16(v);
    }
    *(int4*)((__hip_bfloat16*)(ws + WS_BB_B) + (size_t)n * 192 + k0) = *(int4*)val;
}

// ---------------- mega: bf16 MFMA GEMM + fused LBS epilogue ----------------
// 256 thr = 4 waves split over columns (wn=wave). M=128 batch x N=192 cols, K=192 (3 chunks of 64).
// Grid: x = batch tile (16), y = ntile (79) -> consecutive blocks share the B tile.
#define A_OFF  0          // 128 * 136 = 17408
#define B_OFF  17408      // 192 * 136 = 26112 -> 43520
#define S_VT   65         // vtT word stride (odd -> transpose-friendly banks)
#define S_AT   61         // atrS word stride (61 coprime 32 -> conflict-free)
#define VT_T_OFF 0        // 192*65*4 = 49920
#define ATR_OFF  49920    // 64*61*4 = 15616 -> 65536
#define VTQ_OFF  65536    // 192*4 = 768 -> 66304
#define LBS_OFF  66304    // 320*4 = 1280 -> 67584
#define SMEM_BYTES 67584

__global__ __launch_bounds__(256, 2) void k_mega(
        const char* __restrict__ ws,
        const float* __restrict__ vt,     // [N3]
        const float* __restrict__ lbsw,   // [NV][5]
        float* __restrict__ out) {
    __shared__ __align__(16) unsigned char smem[SMEM_BYTES];
    const unsigned char* AbG = (const unsigned char*)ws + WS_AB_B;
    const unsigned char* BbG = (const unsigned char*)ws + WS_BB_B;
    const float* AtrG = (const float*)(ws + WS_ATR_B);

    const int ntile = blockIdx.y;          // 0..78
    const int b0    = blockIdx.x * 128;    // 16 tiles
    const int t     = threadIdx.x;
    const int lane  = t & 63;
    const int wn    = t >> 6;              // wave: column quarter
    const int l15 = lane & 15, quad = lane >> 4;

    floatx4 acc[8][3];
    #pragma unroll
    for (int f = 0; f < 8; ++f)
        #pragma unroll
        for (int g = 0; g < 3; ++g) {
            floatx4 z = {0.f, 0.f, 0.f, 0.f};
            acc[f][g] = z;
        }

    for (int chunk = 0; chunk < 3; ++chunk) {
        __syncthreads();
        // A: 128 rows x 128 B
        #pragma unroll
        for (int i = 0; i < 4; ++i) {
            int flat = i * 256 + t;
            int row = flat >> 3, piece = flat & 7;
            *(float4*)(smem + A_OFF + row * 136 + piece * 16) =
                *(const float4*)(AbG + (size_t)(b0 + row) * 384 + chunk * 128 + piece * 16);
        }
        // B: 192 rows x 128 B
        #pragma unroll
        for (int i = 0; i < 6; ++i) {
            int flat = i * 256 + t;
            int row = flat >> 3, piece = flat & 7;
            *(float4*)(smem + B_OFF + row * 136 + piece * 16) =
                *(const float4*)(BbG + (size_t)(ntile * 192 + row) * 384 + chunk * 128 + piece * 16);
        }
        __syncthreads();
        #pragma unroll
        for (int ks = 0; ks < 2; ++ks) {
            short8 af[8];
            #pragma unroll
            for (int f = 0; f < 8; ++f)
                af[f] = *(const short8*)(smem + A_OFF + (f * 16 + l15) * 136 + ks * 64 + quad * 16);
            #pragma unroll
            for (int g = 0; g < 3; ++g) {
                short8 bf = *(const short8*)(smem + B_OFF + (wn * 48 + g * 16 + l15) * 136 + ks * 64 + quad * 16);
                #pragma unroll
                for (int f = 0; f < 8; ++f)
                    acc[f][g] = __builtin_amdgcn_mfma_f32_16x16x32_bf16(af[f], bf, acc[f][g], 0, 0, 0);
            }
        }
    }
    __syncthreads();

    float* vtT  = (float*)(smem + VT_T_OFF);   // [192 cols][65]
    float* atrS = (float*)(smem + ATR_OFF);    // [64][61]
    float* vtQ  = (float*)(smem + VTQ_OFF);    // [192]
    float* lbsS = (float*)(smem + LBS_OFF);    // [64][5]

    // stage per-vertex constants once (region disjoint from vtT/atrS)
    if (t < 192) { int n = ntile * 192 + t; vtQ[t] = (n < N3) ? vt[n] : 0.f; }
    for (int i = t; i < 320; i += 256) {
        int v = ntile * 64 + i / 5;
        lbsS[i] = (v < NV) ? lbsw[(size_t)v * 5 + (i % 5)] : 0.f;
    }

    #pragma unroll
    for (int half = 0; half < 2; ++half) {
        __syncthreads();
        // dump acc rows [half*64, half*64+64) -> vtT[col][rl]
        #pragma unroll
        for (int ff = 0; ff < 4; ++ff) {
            int f = half * 4 + ff;
            #pragma unroll
            for (int g = 0; g < 3; ++g) {
                int col = wn * 48 + g * 16 + l15;
                int rl  = ff * 16 + quad * 4;
                #pragma unroll
                for (int r = 0; r < 4; ++r)
                    vtT[col * S_VT + rl + r] = acc[f][g][r];
            }
        }
        for (int i = t; i < 3840; i += 256) {
            int rw = i / 60, cw = i - rw * 60;
            atrS[rw * S_AT + cw] = AtrG[((size_t)b0 + half * 64) * 60 + i];
        }
        __syncthreads();

        // LBS: lane rl = t&63 (batch row), vgrp = t>>6 (16 verts)
        {
            int rl = t & 63;
            int vgrp = t >> 6;
            float ar[60];
            #pragma unroll
            for (int i = 0; i < 60; ++i) ar[i] = atrS[rl * S_AT + i];
            for (int vv = 0; vv < 16; ++vv) {
                int vloc = vgrp * 16 + vv;
                int c0 = vloc * 3;
                float w0 = lbsS[vloc*5+0], w1 = lbsS[vloc*5+1], w2 = lbsS[vloc*5+2],
                      w3 = lbsS[vloc*5+3], w4 = lbsS[vloc*5+4];
                float px = vtT[(c0+0) * S_VT + rl] + vtQ[c0+0];
                float py = vtT[(c0+1) * S_VT + rl] + vtQ[c0+1];
                float pz = vtT[(c0+2) * S_VT + rl] + vtQ[c0+2];
                float y[3];
                #pragma unroll
                for (int r = 0; r < 3; ++r) {
                    float t0 = w0*ar[ 0+r*4+0] + w1*ar[12+r*4+0] + w2*ar[24+r*4+0]
                             + w3*ar[36+r*4+0] + w4*ar[48+r*4+0];
                    float t1 = w0*ar[ 0+r*4+1] + w1*ar[12+r*4+1] + w2*ar[24+r*4+1]
                             + w3*ar[36+r*4+1] + w4*ar[48+r*4+1];
                    float t2 = w0*ar[ 0+r*4+2] + w1*ar[12+r*4+2] + w2*ar[24+r*4+2]
                             + w3*ar[36+r*4+2] + w4*ar[48+r*4+2];
                    float t3 = w0*ar[ 0+r*4+3] + w1*ar[12+r*4+3] + w2*ar[24+r*4+3]
                             + w3*ar[36+r*4+3] + w4*ar[48+r*4+3];
                    y[r] = t0*px + t1*py + t2*pz + t3;
                }
                vtT[(c0+0) * S_VT + rl] = y[0];
                vtT[(c0+1) * S_VT + rl] = y[1];
                vtT[(c0+2) * S_VT + rl] = y[2];
            }
        }
        __syncthreads();
        // transpose out: per row, 3 coalesced dword stores of 64 cols each.
        // Non-temporal: output is write-once/never-re-read -> keep it out of L2/L3
        // so A/B/Atr stay resident and partial lines don't thrash.
        {
            int wv = t >> 6;
            const bool full = (ntile * 192 + 192 <= N3);
            for (int rr = wv; rr < 64; rr += 4) {
                size_t ob = (size_t)(b0 + half * 64 + rr) * N3 + (size_t)ntile * 192;
                if (full) {
                    #pragma unroll
                    for (int e = 0; e < 3; ++e) {
                        int col = e * 64 + lane;
                        __builtin_nontemporal_store(vtT[col * S_VT + rr], &out[ob + col]);
                    }
                } else {
                    #pragma unroll
                    for (int e = 0; e < 3; ++e) {
                        int col = e * 64 + lane;
                        if (ntile * 192 + col < N3)
                            __builtin_nontemporal_store(vtT[col * S_VT + rr], &out[ob + col]);
                    }
                }
            }
        }
    }
}

extern "C" void kernel_launch(void* const* d_in, const int* in_sizes, int n_in,
                              void* d_out, int out_size, void* d_ws, size_t ws_size,
                              hipStream_t stream) {
    const float* shp  = (const float*)d_in[0];
    const float* expn = (const float*)d_in[1];
    const float* neck = (const float*)d_in[2];
    const float* jaw  = (const float*)d_in[3];
    const float* eye  = (const float*)d_in[4];
    const float* vt   = (const float*)d_in[5];
    const float* sdir = (const float*)d_in[6];
    const float* pdir = (const float*)d_in[7];
    const float* jreg = (const float*)d_in[8];
    const float* lbsw = (const float*)d_in[9];
    char* ws  = (char*)d_ws;
    float* out = (float*)d_out;

    k_zero <<<9,   256, 0, stream>>>(ws);
    k_jdirs<<<126, 256, 0, stream>>>(jreg, sdir, vt, ws);
    k_batch<<<8,   256, 0, stream>>>(shp, expn, neck, jaw, eye, ws);
    k_aconv<<<1536, 256, 0, stream>>>(shp, expn, ws);
    k_bconv<<<1422, 256, 0, stream>>>(sdir, pdir, ws);
    // grid swapped: x = batch-tile (fast-varying) so consecutive blocks share a B tile
    k_mega <<<dim3(16, NTIL), 256, 0, stream>>>(ws, vt, lbsw, out);
}

// Round 2
// 281.563 us; speedup vs baseline: 1.2631x; 1.0489x over previous
//
#include <hip/hip_runtime.h>
#include <hip/hip_bf16.h>
#include <math.h>

#define NV   5023
#define N3   15069
#define NB   2048
#define NTIL 79            // ceil(N3/192) column tiles
#define NPAD (NTIL*192)    // 15168 padded B rows

// ---- workspace byte offsets ----
#define WS_JD_B   0          // 2272 floats
#define WS_ATR_B  9216       // 2048*60*4  = 491520
#define WS_AB_B   795648     // 2048*192*2 = 786432 (bf16 A)
#define WS_BB_B   1582080    // 15168*192*2 = 5824512 (bf16 B, n-major, padded)

typedef __attribute__((ext_vector_type(8))) short short8;
typedef __attribute__((ext_vector_type(4))) float floatx4;

static __device__ __forceinline__ unsigned short f2bf(float x) {
    union { __hip_bfloat16 h; unsigned short s; } u;
    u.h = __float2bfloat16(x);
    return u.s;
}
static __device__ __forceinline__ unsigned int pk2(float a, float b) {
    return (unsigned int)f2bf(a) | ((unsigned int)f2bf(b) << 16);
}

// lgkmcnt-only barrier: cross-thread LDS ordering without draining the
// non-temporal store queue (vmcnt) -- stores stay in flight across phases.
#define BAR_LGKM() do { \
    asm volatile("s_waitcnt lgkmcnt(0)" ::: "memory"); \
    __builtin_amdgcn_s_barrier(); \
    asm volatile("" ::: "memory"); \
} while (0)

// ---------------- zero the Jdirs accumulator region ----------------
__global__ void k_zero(char* ws) {
    int i = blockIdx.x * 256 + threadIdx.x;
    if (i < 2272) ((float*)(ws + WS_JD_B))[i] = 0.f;
}

// ---------------- fused: Jdirs (blocks 0..125) + bconv (blocks 126..1547) ----------------
__global__ void k_prep(const float* __restrict__ Jreg,   // [5][NV]
                       const float* __restrict__ sdirs,  // [NV][450] == [N3][150]
                       const float* __restrict__ vt,     // [NV][3]
                       const float* __restrict__ pdirs,  // [36][N3]
                       char* __restrict__ ws) {
    if (blockIdx.x < 126) {
        // ---- Jdirs: 126 slices x 40 verts ----
        int slice = blockIdx.x;
        int start = slice * 40;
        int end   = min(start + 40, NV);
        int t = threadIdx.x;
        int s0 = t, s1 = t + 256;
        float a0[5] = {0,0,0,0,0}, a1[5] = {0,0,0,0,0};
        for (int v = start; v < end; ++v) {
            float w[5];
            #pragma unroll
            for (int j = 0; j < 5; ++j) w[j] = Jreg[j * NV + v];
            float x0 = (s0 < 450) ? sdirs[(size_t)v * 450 + s0]
                     : (s0 < 453 ? vt[v * 3 + (s0 - 450)] : 0.f);
            float x1 = (s1 < 450) ? sdirs[(size_t)v * 450 + s1]
                     : (s1 < 453 ? vt[v * 3 + (s1 - 450)] : 0.f);
            #pragma unroll
            for (int j = 0; j < 5; ++j) { a0[j] += w[j] * x0; a1[j] += w[j] * x1; }
        }
        float* Jd = (float*)(ws + WS_JD_B);
        #pragma unroll
        for (int j = 0; j < 5; ++j) {
            if (s0 < 453) atomicAdd(&Jd[j * 453 + s0], a0[j]);
            if (s1 < 453) atomicAdd(&Jd[j * 453 + s1], a1[j]);
        }
    } else {
        // ---- bconv: build bf16 B [NPAD][192], coalesced 16B writes ----
        int idx = (blockIdx.x - 126) * 256 + threadIdx.x;   // < NPAD*24
        int kg = idx % 24, n = idx / 24;
        int k0 = kg * 8;
        __hip_bfloat16 val[8];
        #pragma unroll
        for (int e = 0; e < 8; ++e) {
            int k = k0 + e;
            float v = 0.f;
            if (n < N3) {
                if (k < 150)      v = sdirs[(size_t)n * 150 + k];
                else if (k < 186) v = pdirs[(size_t)(k - 150) * N3 + n];
            }
            val[e] = __float2bfloat16(v);
        }
        *(int4*)((__hip_bfloat16*)(ws + WS_BB_B) + (size_t)n * 192 + k0) = *(int4*)val;
    }
}

// ---------------- per-batch: J GEMV, rodrigues, chain -> Atr; writes bf16 A row directly ----------------
// 32 blocks x 64 threads (one thread per batch element)
__global__ void k_batch(const float* __restrict__ shp,
                        const float* __restrict__ expn,
                        const float* __restrict__ neck,
                        const float* __restrict__ jaw,
                        const float* __restrict__ eye,
                        char* __restrict__ ws) {
    __shared__ float JdL[2265];
    {
        const float* Jd = (const float*)(ws + WS_JD_B);
        for (int i = threadIdx.x; i < 2265; i += 64) JdL[i] = Jd[i];
    }
    __syncthreads();
    int b = blockIdx.x * 64 + threadIdx.x;
    float* Atr = (float*)(ws + WS_ATR_B) + (size_t)b * 60;
    unsigned int* A32 = (unsigned int*)((char*)ws + WS_AB_B + (size_t)b * 384);

    float J[15];
    #pragma unroll
    for (int jk = 0; jk < 15; ++jk) J[jk] = JdL[(jk / 3) * 453 + 450 + (jk % 3)];

    // shape betas: 25 vectorized float4 loads (row = 400 B, 16B-aligned)
    for (int l4 = 0; l4 < 25; ++l4) {
        float4 be = *(const float4*)(shp + (size_t)b * 100 + l4 * 4);
        A32[2*l4]     = pk2(be.x, be.y);
        A32[2*l4 + 1] = pk2(be.z, be.w);
        float bev[4] = {be.x, be.y, be.z, be.w};
        #pragma unroll
        for (int e = 0; e < 4; ++e) {
            int l = l4 * 4 + e;
            #pragma unroll
            for (int jj = 0; jj < 5; ++jj)
                #pragma unroll
                for (int kk = 0; kk < 3; ++kk)
                    J[jj * 3 + kk] += JdL[jj * 453 + kk * 150 + l] * bev[e];
        }
    }
    // expression betas: 25 float2 loads (row = 200 B, 8B-aligned)
    for (int l2 = 0; l2 < 25; ++l2) {
        float2 be = *(const float2*)(expn + (size_t)b * 50 + l2 * 2);
        A32[50 + l2] = pk2(be.x, be.y);
        float bev[2] = {be.x, be.y};
        #pragma unroll
        for (int e = 0; e < 2; ++e) {
            int l = 100 + l2 * 2 + e;
            #pragma unroll
            for (int jj = 0; jj < 5; ++jj)
                #pragma unroll
                for (int kk = 0; kk < 3; ++kk)
                    J[jj * 3 + kk] += JdL[jj * 453 + kk * 150 + l] * bev[e];
        }
    }

    float R[5][9];
    for (int jj = 0; jj < 5; ++jj) {
        float rx, ry, rz;
        if (jj == 0)      { rx = 0.f; ry = 0.f; rz = 0.f; }
        else if (jj == 1) { rx = neck[b*3]; ry = neck[b*3+1]; rz = neck[b*3+2]; }
        else if (jj == 2) { rx = jaw[b*3];  ry = jaw[b*3+1];  rz = jaw[b*3+2];  }
        else if (jj == 3) { rx = eye[b*6];  ry = eye[b*6+1];  rz = eye[b*6+2];  }
        else              { rx = eye[b*6+3]; ry = eye[b*6+4]; rz = eye[b*6+5];  }
        float ax = rx + 1e-8f, ay = ry + 1e-8f, az = rz + 1e-8f;
        float angle = sqrtf(ax*ax + ay*ay + az*az);
        float inv = 1.f / angle;
        float ux = rx * inv, uy = ry * inv, uz = rz * inv;
        float c = cosf(angle), s = sinf(angle);
        float K[9] = {0.f, -uz, uy,  uz, 0.f, -ux,  -uy, ux, 0.f};
        float KK[9];
        #pragma unroll
        for (int r = 0; r < 3; ++r)
            #pragma unroll
            for (int cc = 0; cc < 3; ++cc) {
                float a = 0.f;
                #pragma unroll
                for (int m = 0; m < 3; ++m) a += K[r*3+m] * K[m*3+cc];
                KK[r*3+cc] = a;
            }
        #pragma unroll
        for (int e = 0; e < 9; ++e) R[jj][e] = s * K[e] + (1.f - c) * KK[e];
        R[jj][0] += 1.f; R[jj][4] += 1.f; R[jj][8] += 1.f;
    }

    // pose_feature -> bf16 A cols 150..185 directly
    float pf_loc[36];
    #pragma unroll
    for (int jj = 1; jj < 5; ++jj)
        #pragma unroll
        for (int e = 0; e < 9; ++e)
            pf_loc[(jj-1)*9 + e] = R[jj][e] - ((e == 0 || e == 4 || e == 8) ? 1.f : 0.f);
    #pragma unroll
    for (int i = 0; i < 18; ++i) A32[75 + i] = pk2(pf_loc[2*i], pf_loc[2*i + 1]);
    A32[93] = 0u; A32[94] = 0u; A32[95] = 0u;

    float G[5][12];
    #pragma unroll
    for (int r = 0; r < 3; ++r) {
        #pragma unroll
        for (int cc = 0; cc < 3; ++cc) G[0][r*4+cc] = R[0][r*3+cc];
        G[0][r*4+3] = J[r];
    }
    const int par[5] = {-1, 0, 1, 1, 1};
    for (int jj = 1; jj < 5; ++jj) {
        int p = par[jj];
        float rel[3];
        #pragma unroll
        for (int r = 0; r < 3; ++r) rel[r] = J[jj*3+r] - J[p*3+r];
        #pragma unroll
        for (int r = 0; r < 3; ++r) {
            #pragma unroll
            for (int cc = 0; cc < 3; ++cc) {
                float a = 0.f;
                #pragma unroll
                for (int m = 0; m < 3; ++m) a += G[p][r*4+m] * R[jj][m*3+cc];
                G[jj][r*4+cc] = a;
            }
            float tt = G[p][r*4+3];
            #pragma unroll
            for (int m = 0; m < 3; ++m) tt += G[p][r*4+m] * rel[m];
            G[jj][r*4+3] = tt;
        }
    }
    for (int jj = 0; jj < 5; ++jj)
        #pragma unroll
        for (int r = 0; r < 3; ++r) {
            float tc = 0.f;
            #pragma unroll
            for (int m = 0; m < 3; ++m) tc += G[jj][r*4+m] * J[jj*3+m];
            Atr[jj*12 + r*4 + 0] = G[jj][r*4+0];
            Atr[jj*12 + r*4 + 1] = G[jj][r*4+1];
            Atr[jj*12 + r*4 + 2] = G[jj][r*4+2];
            Atr[jj*12 + r*4 + 3] = G[jj][r*4+3] - tc;
        }
}

// ---------------- mega: bf16 MFMA GEMM + fused LBS epilogue ----------------
// 256 thr = 4 waves split over columns (wn=wave). M=128 batch x N=192 cols, K=192 (3 chunks of 64).
// Grid: x = batch tile (16), y = ntile (79) -> consecutive blocks share the B tile.
// Epilogue processes output rows in QUARTERS (32 rows) so LDS fits 3 blocks/CU.
#define A_OFF  0          // 128 * 136 = 17408
#define B_OFF  17408      // 192 * 136 = 26112 -> 43520
#define S_VT   33         // vtT word stride (33 coprime-ish with 32 -> conflict-free dword phases)
#define S_AT   61         // atrS word stride (61 coprime 32 -> conflict-free)
#define VT_T_OFF 0        // 192*33*4 = 25344
#define ATR_OFF  25344    // 32*61*4 = 7808 -> 33152
#define VTQ_OFF  33152    // 192*4 = 768 -> 33920
#define LBS_OFF  33920    // 320*4 = 1280 -> 35200
#define SMEM_BYTES 43520  // GEMM stage (A+B) dominates

__global__ __launch_bounds__(256, 3) void k_mega(
        const char* __restrict__ ws,
        const float* __restrict__ vt,     // [N3]
        const float* __restrict__ lbsw,   // [NV][5]
        float* __restrict__ out) {
    __shared__ __align__(16) unsigned char smem[SMEM_BYTES];
    const unsigned char* AbG = (const unsigned char*)ws + WS_AB_B;
    const unsigned char* BbG = (const unsigned char*)ws + WS_BB_B;
    const float* AtrG = (const float*)(ws + WS_ATR_B);

    const int ntile = blockIdx.y;          // 0..78
    const int b0    = blockIdx.x * 128;    // 16 tiles
    const int t     = threadIdx.x;
    const int lane  = t & 63;
    const int wn    = t >> 6;              // wave: column quarter
    const int l15 = lane & 15, quad = lane >> 4;

    floatx4 acc[8][3];
    #pragma unroll
    for (int f = 0; f < 8; ++f)
        #pragma unroll
        for (int g = 0; g < 3; ++g) {
            floatx4 z = {0.f, 0.f, 0.f, 0.f};
            acc[f][g] = z;
        }

    for (int chunk = 0; chunk < 3; ++chunk) {
        __syncthreads();
        // A: 128 rows x 128 B
        #pragma unroll
        for (int i = 0; i < 4; ++i) {
            int flat = i * 256 + t;
            int row = flat >> 3, piece = flat & 7;
            *(float4*)(smem + A_OFF + row * 136 + piece * 16) =
                *(const float4*)(AbG + (size_t)(b0 + row) * 384 + chunk * 128 + piece * 16);
        }
        // B: 192 rows x 128 B
        #pragma unroll
        for (int i = 0; i < 6; ++i) {
            int flat = i * 256 + t;
            int row = flat >> 3, piece = flat & 7;
            *(float4*)(smem + B_OFF + row * 136 + piece * 16) =
                *(const float4*)(BbG + (size_t)(ntile * 192 + row) * 384 + chunk * 128 + piece * 16);
        }
        __syncthreads();
        #pragma unroll
        for (int ks = 0; ks < 2; ++ks) {
            short8 af[8];
            #pragma unroll
            for (int f = 0; f < 8; ++f)
                af[f] = *(const short8*)(smem + A_OFF + (f * 16 + l15) * 136 + ks * 64 + quad * 16);
            #pragma unroll
            for (int g = 0; g < 3; ++g) {
                short8 bf = *(const short8*)(smem + B_OFF + (wn * 48 + g * 16 + l15) * 136 + ks * 64 + quad * 16);
                #pragma unroll
                for (int f = 0; f < 8; ++f)
                    acc[f][g] = __builtin_amdgcn_mfma_f32_16x16x32_bf16(af[f], bf, acc[f][g], 0, 0, 0);
            }
        }
    }
    __syncthreads();

    float* vtT  = (float*)(smem + VT_T_OFF);   // [192 cols][33]
    float* atrS = (float*)(smem + ATR_OFF);    // [32][61]
    float* vtQ  = (float*)(smem + VTQ_OFF);    // [192]
    float* lbsS = (float*)(smem + LBS_OFF);    // [64][5]

    // stage per-vertex constants once (region disjoint from vtT/atrS)
    if (t < 192) { int n = ntile * 192 + t; vtQ[t] = (n < N3) ? vt[n] : 0.f; }
    for (int i = t; i < 320; i += 256) {
        int v = ntile * 64 + i / 5;
        lbsS[i] = (v < NV) ? lbsw[(size_t)v * 5 + (i % 5)] : 0.f;
    }

    #pragma unroll
    for (int q = 0; q < 4; ++q) {
        BAR_LGKM();   // vtT/atrS reuse hazard only (LDS) -- NT stores stay in flight
        // dump acc rows [q*32, q*32+32) -> vtT[col][rl]
        #pragma unroll
        for (int ff2 = 0; ff2 < 2; ++ff2) {
            int f = q * 2 + ff2;
            #pragma unroll
            for (int g = 0; g < 3; ++g) {
                int col = wn * 48 + g * 16 + l15;
                int rl  = ff2 * 16 + quad * 4;
                #pragma unroll
                for (int r = 0; r < 4; ++r)
                    vtT[col * S_VT + rl + r] = acc[f][g][r];
            }
        }
        for (int i = t; i < 1920; i += 256) {
            int rw = i / 60, cw = i - rw * 60;
            atrS[rw * S_AT + cw] = AtrG[((size_t)(b0 + q * 32)) * 60 + i];
        }
        BAR_LGKM();

        // LBS: rl = t&31 (batch row within quarter), vgrp = t>>5 (8 verts each)
        {
            int rl = t & 31;
            int vgrp = t >> 5;
            float ar[60];
            #pragma unroll
            for (int i = 0; i < 60; ++i) ar[i] = atrS[rl * S_AT + i];
            #pragma unroll
            for (int vv = 0; vv < 8; ++vv) {
                int vloc = vgrp * 8 + vv;
                int c0 = vloc * 3;
                float w0 = lbsS[vloc*5+0], w1 = lbsS[vloc*5+1], w2 = lbsS[vloc*5+2],
                      w3 = lbsS[vloc*5+3], w4 = lbsS[vloc*5+4];
                float px = vtT[(c0+0) * S_VT + rl] + vtQ[c0+0];
                float py = vtT[(c0+1) * S_VT + rl] + vtQ[c0+1];
                float pz = vtT[(c0+2) * S_VT + rl] + vtQ[c0+2];
                float y[3];
                #pragma unroll
                for (int r = 0; r < 3; ++r) {
                    float t0 = w0*ar[ 0+r*4+0] + w1*ar[12+r*4+0] + w2*ar[24+r*4+0]
                             + w3*ar[36+r*4+0] + w4*ar[48+r*4+0];
                    float t1 = w0*ar[ 0+r*4+1] + w1*ar[12+r*4+1] + w2*ar[24+r*4+1]
                             + w3*ar[36+r*4+1] + w4*ar[48+r*4+1];
                    float t2 = w0*ar[ 0+r*4+2] + w1*ar[12+r*4+2] + w2*ar[24+r*4+2]
                             + w3*ar[36+r*4+2] + w4*ar[48+r*4+2];
                    float t3 = w0*ar[ 0+r*4+3] + w1*ar[12+r*4+3] + w2*ar[24+r*4+3]
                             + w3*ar[36+r*4+3] + w4*ar[48+r*4+3];
                    y[r] = t0*px + t1*py + t2*pz + t3;
                }
                vtT[(c0+0) * S_VT + rl] = y[0];
                vtT[(c0+1) * S_VT + rl] = y[1];
                vtT[(c0+2) * S_VT + rl] = y[2];
            }
        }
        BAR_LGKM();
        // transpose out: per row, 3 coalesced dword NT stores of 64 cols each
        {
            int wv = t >> 6;
            const bool full = (ntile * 192 + 192 <= N3);
            for (int rr = wv; rr < 32; rr += 4) {
                size_t ob = (size_t)(b0 + q * 32 + rr) * N3 + (size_t)ntile * 192;
                if (full) {
                    #pragma unroll
                    for (int e = 0; e < 3; ++e) {
                        int col = e * 64 + lane;
                        __builtin_nontemporal_store(vtT[col * S_VT + rr], &out[ob + col]);
                    }
                } else {
                    #pragma unroll
                    for (int e = 0; e < 3; ++e) {
                        int col = e * 64 + lane;
                        if (ntile * 192 + col < N3)
                            __builtin_nontemporal_store(vtT[col * S_VT + rr], &out[ob + col]);
                    }
                }
            }
        }
    }
}

extern "C" void kernel_launch(void* const* d_in, const int* in_sizes, int n_in,
                              void* d_out, int out_size, void* d_ws, size_t ws_size,
                              hipStream_t stream) {
    const float* shp  = (const float*)d_in[0];
    const float* expn = (const float*)d_in[1];
    const float* neck = (const float*)d_in[2];
    const float* jaw  = (const float*)d_in[3];
    const float* eye  = (const float*)d_in[4];
    const float* vt   = (const float*)d_in[5];
    const float* sdir = (const float*)d_in[6];
    const float* pdir = (const float*)d_in[7];
    const float* jreg = (const float*)d_in[8];
    const float* lbsw = (const float*)d_in[9];
    char* ws  = (char*)d_ws;
    float* out = (float*)d_out;

    k_zero <<<9,    256, 0, stream>>>(ws);
    k_prep <<<1548, 256, 0, stream>>>(jreg, sdir, vt, pdir, ws);
    k_batch<<<32,    64, 0, stream>>>(shp, expn, neck, jaw, eye, ws);
    k_mega <<<dim3(16, NTIL), 256, 0, stream>>>(ws, vt, lbsw, out);
}

// Round 3
// 255.487 us; speedup vs baseline: 1.3921x; 1.1021x over previous
//
#include <hip/hip_runtime.h>
#include <hip/hip_bf16.h>
#include <math.h>

#define NV   5023
#define N3   15069
#define NB   2048
#define NTIL 79            // ceil(N3/192) column tiles
#define NPAD (NTIL*192)    // 15168 padded B rows

// ---- workspace byte offsets ----
#define WS_JD_B   0          // 2272 floats
#define WS_ATR_B  9216       // 2048*60*4  = 491520
#define WS_AB_B   795648     // 2048*192*2 = 786432 (bf16 A)
#define WS_BB_B   1582080    // 15168*192*2 = 5824512 (bf16 B, n-major, padded)

// k_prep block ranges
#define GP_J 126             // jdirs slices
#define GP_S 1067            // sdirs->B cols 0..143 (NPAD*18 int4 / 256)
#define GP_P 237             // pose cols 144..191 (NPAD/64)

typedef __attribute__((ext_vector_type(8))) short short8;
typedef __attribute__((ext_vector_type(4))) float floatx4;

static __device__ __forceinline__ unsigned short f2bf(float x) {
    union { __hip_bfloat16 h; unsigned short s; } u;
    u.h = __float2bfloat16(x);
    return u.s;
}
static __device__ __forceinline__ unsigned int pk2(float a, float b) {
    return (unsigned int)f2bf(a) | ((unsigned int)f2bf(b) << 16);
}

// lgkmcnt-only barrier: cross-thread LDS ordering without draining the
// non-temporal store queue (vmcnt) -- stores stay in flight across phases.
#define BAR_LGKM() do { \
    asm volatile("s_waitcnt lgkmcnt(0)" ::: "memory"); \
    __builtin_amdgcn_s_barrier(); \
    asm volatile("" ::: "memory"); \
} while (0)

// ---------------- fused prep: jdirs | B cols 0..143 | B cols 144..191 ----------------
__global__ void k_prep(const float* __restrict__ Jreg,   // [5][NV]
                       const float* __restrict__ sdirs,  // [NV][450] == [N3][150]
                       const float* __restrict__ vt,     // [NV][3]
                       const float* __restrict__ pdirs,  // [36][N3]
                       char* __restrict__ ws) {
    __shared__ float JregL[200];      // jdirs: 5 joints x 40 verts
    __shared__ float PL[36][65];      // pose transpose staging (+pad)
    const int t = threadIdx.x;

    if (blockIdx.x < GP_J) {
        // ---- Jdirs: 126 slices x 40 verts, Jreg staged in LDS ----
        int slice = blockIdx.x;
        int start = slice * 40;
        int end   = min(start + 40, NV);
        if (t < 200) {
            int j = t / 40, vl = t % 40;
            int v = start + vl;
            JregL[t] = (v < NV) ? Jreg[j * NV + v] : 0.f;
        }
        __syncthreads();
        int s0 = t, s1 = t + 256;
        float a0[5] = {0,0,0,0,0}, a1[5] = {0,0,0,0,0};
        #pragma unroll 2
        for (int v = start; v < end; ++v) {
            int vl = v - start;
            float x0 = (s0 < 450) ? sdirs[(size_t)v * 450 + s0]
                     : (s0 < 453 ? vt[v * 3 + (s0 - 450)] : 0.f);
            float x1 = (s1 < 450) ? sdirs[(size_t)v * 450 + s1]
                     : (s1 < 453 ? vt[v * 3 + (s1 - 450)] : 0.f);
            #pragma unroll
            for (int j = 0; j < 5; ++j) {
                float w = JregL[j * 40 + vl];
                a0[j] += w * x0; a1[j] += w * x1;
            }
        }
        float* Jd = (float*)(ws + WS_JD_B);
        #pragma unroll
        for (int j = 0; j < 5; ++j) {
            if (s0 < 453) atomicAdd(&Jd[j * 453 + s0], a0[j]);
            if (s1 < 453) atomicAdd(&Jd[j * 453 + s1], a1[j]);
        }
    } else if (blockIdx.x < GP_J + GP_S) {
        // ---- B cols 0..143: branch-free, aligned float2 reads, int4 writes ----
        int idx = (blockIdx.x - GP_J) * 256 + t;
        if (idx < NPAD * 18) {
            int n = idx / 18, g = idx % 18;
            __hip_bfloat16* dst = (__hip_bfloat16*)(ws + WS_BB_B) + (size_t)n * 192 + g * 8;
            if (n < N3) {
                const float* src = sdirs + (size_t)n * 150 + g * 8;   // 8B-aligned
                float2 p0 = *(const float2*)(src);
                float2 p1 = *(const float2*)(src + 2);
                float2 p2 = *(const float2*)(src + 4);
                float2 p3 = *(const float2*)(src + 6);
                unsigned int w[4] = { pk2(p0.x, p0.y), pk2(p1.x, p1.y),
                                      pk2(p2.x, p2.y), pk2(p3.x, p3.y) };
                *(int4*)dst = *(int4*)w;
            } else {
                int4 z = {0, 0, 0, 0};
                *(int4*)dst = z;
            }
        }
    } else {
        // ---- B cols 144..191: pdirs transposed via LDS (coalesced both sides) ----
        int pb = blockIdx.x - (GP_J + GP_S);
        int n0 = pb * 64;
        #pragma unroll
        for (int j = 0; j < 9; ++j) {
            int flat = j * 256 + t;          // < 2304 = 36*64
            int k = flat >> 6, i = flat & 63;
            int n = n0 + i;
            PL[k][i] = (n < N3) ? pdirs[(size_t)k * N3 + n] : 0.f;
        }
        __syncthreads();
        #pragma unroll
        for (int j = 0; j < 2; ++j) {
            int idx2 = j * 256 + t;
            if (idx2 < 384) {                // 64 rows x 6 int4
                int r = idx2 / 6, g = idx2 % 6;
                int n = n0 + r;
                int k0 = 144 + g * 8;
                __hip_bfloat16 val[8];
                #pragma unroll
                for (int e = 0; e < 8; ++e) {
                    int k = k0 + e;
                    float v = 0.f;
                    if (k < 150)      v = (n < N3) ? sdirs[(size_t)n * 150 + k] : 0.f;
                    else if (k < 186) v = PL[k - 150][r];
                    val[e] = __float2bfloat16(v);
                }
                *(int4*)((__hip_bfloat16*)(ws + WS_BB_B) + (size_t)n * 192 + k0) = *(int4*)val;
            }
        }
    }
}

// ---------------- per-batch: J GEMV, rodrigues, chain -> Atr; writes bf16 A row directly ----------------
// 32 blocks x 64 threads (one thread per batch element)
__global__ void k_batch(const float* __restrict__ shp,
                        const float* __restrict__ expn,
                        const float* __restrict__ neck,
                        const float* __restrict__ jaw,
                        const float* __restrict__ eye,
                        char* __restrict__ ws) {
    __shared__ float JdL[2265];
    {
        const float* Jd = (const float*)(ws + WS_JD_B);
        for (int i = threadIdx.x; i < 2265; i += 64) JdL[i] = Jd[i];
    }
    __syncthreads();
    int b = blockIdx.x * 64 + threadIdx.x;
    float* Atr = (float*)(ws + WS_ATR_B) + (size_t)b * 60;
    unsigned int* A32 = (unsigned int*)((char*)ws + WS_AB_B + (size_t)b * 384);

    float J[15];
    #pragma unroll
    for (int jk = 0; jk < 15; ++jk) J[jk] = JdL[(jk / 3) * 453 + 450 + (jk % 3)];

    // shape betas: 25 vectorized float4 loads (row = 400 B, 16B-aligned)
    for (int l4 = 0; l4 < 25; ++l4) {
        float4 be = *(const float4*)(shp + (size_t)b * 100 + l4 * 4);
        A32[2*l4]     = pk2(be.x, be.y);
        A32[2*l4 + 1] = pk2(be.z, be.w);
        float bev[4] = {be.x, be.y, be.z, be.w};
        #pragma unroll
        for (int e = 0; e < 4; ++e) {
            int l = l4 * 4 + e;
            #pragma unroll
            for (int jj = 0; jj < 5; ++jj)
                #pragma unroll
                for (int kk = 0; kk < 3; ++kk)
                    J[jj * 3 + kk] += JdL[jj * 453 + kk * 150 + l] * bev[e];
        }
    }
    // expression betas: 25 float2 loads (row = 200 B, 8B-aligned)
    for (int l2 = 0; l2 < 25; ++l2) {
        float2 be = *(const float2*)(expn + (size_t)b * 50 + l2 * 2);
        A32[50 + l2] = pk2(be.x, be.y);
        float bev[2] = {be.x, be.y};
        #pragma unroll
        for (int e = 0; e < 2; ++e) {
            int l = 100 + l2 * 2 + e;
            #pragma unroll
            for (int jj = 0; jj < 5; ++jj)
                #pragma unroll
                for (int kk = 0; kk < 3; ++kk)
                    J[jj * 3 + kk] += JdL[jj * 453 + kk * 150 + l] * bev[e];
        }
    }

    float R[5][9];
    for (int jj = 0; jj < 5; ++jj) {
        float rx, ry, rz;
        if (jj == 0)      { rx = 0.f; ry = 0.f; rz = 0.f; }
        else if (jj == 1) { rx = neck[b*3]; ry = neck[b*3+1]; rz = neck[b*3+2]; }
        else if (jj == 2) { rx = jaw[b*3];  ry = jaw[b*3+1];  rz = jaw[b*3+2];  }
        else if (jj == 3) { rx = eye[b*6];  ry = eye[b*6+1];  rz = eye[b*6+2];  }
        else              { rx = eye[b*6+3]; ry = eye[b*6+4]; rz = eye[b*6+5];  }
        float ax = rx + 1e-8f, ay = ry + 1e-8f, az = rz + 1e-8f;
        float angle = sqrtf(ax*ax + ay*ay + az*az);
        float inv = 1.f / angle;
        float ux = rx * inv, uy = ry * inv, uz = rz * inv;
        float c = cosf(angle), s = sinf(angle);
        float K[9] = {0.f, -uz, uy,  uz, 0.f, -ux,  -uy, ux, 0.f};
        float KK[9];
        #pragma unroll
        for (int r = 0; r < 3; ++r)
            #pragma unroll
            for (int cc = 0; cc < 3; ++cc) {
                float a = 0.f;
                #pragma unroll
                for (int m = 0; m < 3; ++m) a += K[r*3+m] * K[m*3+cc];
                KK[r*3+cc] = a;
            }
        #pragma unroll
        for (int e = 0; e < 9; ++e) R[jj][e] = s * K[e] + (1.f - c) * KK[e];
        R[jj][0] += 1.f; R[jj][4] += 1.f; R[jj][8] += 1.f;
    }

    // pose_feature -> bf16 A cols 150..185 directly
    float pf_loc[36];
    #pragma unroll
    for (int jj = 1; jj < 5; ++jj)
        #pragma unroll
        for (int e = 0; e < 9; ++e)
            pf_loc[(jj-1)*9 + e] = R[jj][e] - ((e == 0 || e == 4 || e == 8) ? 1.f : 0.f);
    #pragma unroll
    for (int i = 0; i < 18; ++i) A32[75 + i] = pk2(pf_loc[2*i], pf_loc[2*i + 1]);
    A32[93] = 0u; A32[94] = 0u; A32[95] = 0u;

    float G[5][12];
    #pragma unroll
    for (int r = 0; r < 3; ++r) {
        #pragma unroll
        for (int cc = 0; cc < 3; ++cc) G[0][r*4+cc] = R[0][r*3+cc];
        G[0][r*4+3] = J[r];
    }
    const int par[5] = {-1, 0, 1, 1, 1};
    for (int jj = 1; jj < 5; ++jj) {
        int p = par[jj];
        float rel[3];
        #pragma unroll
        for (int r = 0; r < 3; ++r) rel[r] = J[jj*3+r] - J[p*3+r];
        #pragma unroll
        for (int r = 0; r < 3; ++r) {
            #pragma unroll
            for (int cc = 0; cc < 3; ++cc) {
                float a = 0.f;
                #pragma unroll
                for (int m = 0; m < 3; ++m) a += G[p][r*4+m] * R[jj][m*3+cc];
                G[jj][r*4+cc] = a;
            }
            float tt = G[p][r*4+3];
            #pragma unroll
            for (int m = 0; m < 3; ++m) tt += G[p][r*4+m] * rel[m];
            G[jj][r*4+3] = tt;
        }
    }
    for (int jj = 0; jj < 5; ++jj)
        #pragma unroll
        for (int r = 0; r < 3; ++r) {
            float tc = 0.f;
            #pragma unroll
            for (int m = 0; m < 3; ++m) tc += G[jj][r*4+m] * J[jj*3+m];
            Atr[jj*12 + r*4 + 0] = G[jj][r*4+0];
            Atr[jj*12 + r*4 + 1] = G[jj][r*4+1];
            Atr[jj*12 + r*4 + 2] = G[jj][r*4+2];
            Atr[jj*12 + r*4 + 3] = G[jj][r*4+3] - tc;
        }
}

// ---------------- mega: bf16 MFMA GEMM + fused LBS epilogue ----------------
// M=64 batch x N=192 cols per block, K=192 (3 chunks of 64). 4 waves split over columns.
// Static acc = 48 AGPR (was 96) -> combined regs fit the (256,3) budget, no spill.
// Grid: x = batch tile (32), y = ntile (79) -> consecutive blocks share the B tile.
#define A_OFF  0          // 64 * 136 = 8704
#define B_OFF  8704       // 192 * 136 = 26112 -> 34816
#define S_VT   33         // vtT word stride
#define S_AT   61         // atrS word stride (61 coprime 32 -> conflict-free)
#define VT_T_OFF 0        // 192*33*4 = 25344
#define ATR_OFF  25344    // 32*61*4 = 7808 -> 33152
#define VTQ_OFF  33152    // 192*4 = 768 -> 33920
#define LBS_OFF  33920    // 320*4 = 1280 -> 35200
#define SMEM_BYTES 35200  // epilogue union slightly exceeds GEMM stage (34816)

__global__ __launch_bounds__(256, 3) void k_mega(
        const char* __restrict__ ws,
        const float* __restrict__ vt,     // [N3]
        const float* __restrict__ lbsw,   // [NV][5]
        float* __restrict__ out) {
    __shared__ __align__(16) unsigned char smem[SMEM_BYTES];
    const unsigned char* AbG = (const unsigned char*)ws + WS_AB_B;
    const unsigned char* BbG = (const unsigned char*)ws + WS_BB_B;
    const float* AtrG = (const float*)(ws + WS_ATR_B);

    const int ntile = blockIdx.y;          // 0..78
    const int b0    = blockIdx.x * 64;     // 32 tiles
    const int t     = threadIdx.x;
    const int lane  = t & 63;
    const int wn    = t >> 6;              // wave: column quarter
    const int l15 = lane & 15, quad = lane >> 4;

    floatx4 acc[4][3];
    #pragma unroll
    for (int f = 0; f < 4; ++f)
        #pragma unroll
        for (int g = 0; g < 3; ++g) {
            floatx4 z = {0.f, 0.f, 0.f, 0.f};
            acc[f][g] = z;
        }

    for (int chunk = 0; chunk < 3; ++chunk) {
        __syncthreads();
        // A: 64 rows x 128 B
        #pragma unroll
        for (int i = 0; i < 2; ++i) {
            int flat = i * 256 + t;
            int row = flat >> 3, piece = flat & 7;
            *(float4*)(smem + A_OFF + row * 136 + piece * 16) =
                *(const float4*)(AbG + (size_t)(b0 + row) * 384 + chunk * 128 + piece * 16);
        }
        // B: 192 rows x 128 B
        #pragma unroll
        for (int i = 0; i < 6; ++i) {
            int flat = i * 256 + t;
            int row = flat >> 3, piece = flat & 7;
            *(float4*)(smem + B_OFF + row * 136 + piece * 16) =
                *(const float4*)(BbG + (size_t)(ntile * 192 + row) * 384 + chunk * 128 + piece * 16);
        }
        __syncthreads();
        #pragma unroll
        for (int ks = 0; ks < 2; ++ks) {
            short8 af[4];
            #pragma unroll
            for (int f = 0; f < 4; ++f)
                af[f] = *(const short8*)(smem + A_OFF + (f * 16 + l15) * 136 + ks * 64 + quad * 16);
            #pragma unroll
            for (int g = 0; g < 3; ++g) {
                short8 bf = *(const short8*)(smem + B_OFF + (wn * 48 + g * 16 + l15) * 136 + ks * 64 + quad * 16);
                #pragma unroll
                for (int f = 0; f < 4; ++f)
                    acc[f][g] = __builtin_amdgcn_mfma_f32_16x16x32_bf16(af[f], bf, acc[f][g], 0, 0, 0);
            }
        }
    }
    __syncthreads();

    float* vtT  = (float*)(smem + VT_T_OFF);   // [192 cols][33]
    float* atrS = (float*)(smem + ATR_OFF);    // [32][61]
    float* vtQ  = (float*)(smem + VTQ_OFF);    // [192]
    float* lbsS = (float*)(smem + LBS_OFF);    // [64][5]

    // stage per-vertex constants once (after GEMM sync; ordered by next barrier)
    if (t < 192) { int n = ntile * 192 + t; vtQ[t] = (n < N3) ? vt[n] : 0.f; }
    for (int i = t; i < 320; i += 256) {
        int v = ntile * 64 + i / 5;
        lbsS[i] = (v < NV) ? lbsw[(size_t)v * 5 + (i % 5)] : 0.f;
    }

    #pragma unroll
    for (int q = 0; q < 2; ++q) {
        BAR_LGKM();   // vtT/atrS reuse hazard only (LDS) -- NT stores stay in flight
        // dump acc rows [q*32, q*32+32) -> vtT[col][rl]
        #pragma unroll
        for (int ff2 = 0; ff2 < 2; ++ff2) {
            int f = q * 2 + ff2;
            #pragma unroll
            for (int g = 0; g < 3; ++g) {
                int col = wn * 48 + g * 16 + l15;
                int rl  = ff2 * 16 + quad * 4;
                #pragma unroll
                for (int r = 0; r < 4; ++r)
                    vtT[col * S_VT + rl + r] = acc[f][g][r];
            }
        }
        for (int i = t; i < 1920; i += 256) {
            int rw = i / 60, cw = i - rw * 60;
            atrS[rw * S_AT + cw] = AtrG[((size_t)(b0 + q * 32)) * 60 + i];
        }
        BAR_LGKM();

        // LBS: rl = t&31 (batch row within quarter), vgrp = t>>5 (8 verts each)
        {
            int rl = t & 31;
            int vgrp = t >> 5;
            float ar[60];
            #pragma unroll
            for (int i = 0; i < 60; ++i) ar[i] = atrS[rl * S_AT + i];
            #pragma unroll
            for (int vv = 0; vv < 8; ++vv) {
                int vloc = vgrp * 8 + vv;
                int c0 = vloc * 3;
                float w0 = lbsS[vloc*5+0], w1 = lbsS[vloc*5+1], w2 = lbsS[vloc*5+2],
                      w3 = lbsS[vloc*5+3], w4 = lbsS[vloc*5+4];
                float px = vtT[(c0+0) * S_VT + rl] + vtQ[c0+0];
                float py = vtT[(c0+1) * S_VT + rl] + vtQ[c0+1];
                float pz = vtT[(c0+2) * S_VT + rl] + vtQ[c0+2];
                float y[3];
                #pragma unroll
                for (int r = 0; r < 3; ++r) {
                    float t0 = w0*ar[ 0+r*4+0] + w1*ar[12+r*4+0] + w2*ar[24+r*4+0]
                             + w3*ar[36+r*4+0] + w4*ar[48+r*4+0];
                    float t1 = w0*ar[ 0+r*4+1] + w1*ar[12+r*4+1] + w2*ar[24+r*4+1]
                             + w3*ar[36+r*4+1] + w4*ar[48+r*4+1];
                    float t2 = w0*ar[ 0+r*4+2] + w1*ar[12+r*4+2] + w2*ar[24+r*4+2]
                             + w3*ar[36+r*4+2] + w4*ar[48+r*4+2];
                    float t3 = w0*ar[ 0+r*4+3] + w1*ar[12+r*4+3] + w2*ar[24+r*4+3]
                             + w3*ar[36+r*4+3] + w4*ar[48+r*4+3];
                    y[r] = t0*px + t1*py + t2*pz + t3;
                }
                vtT[(c0+0) * S_VT + rl] = y[0];
                vtT[(c0+1) * S_VT + rl] = y[1];
                vtT[(c0+2) * S_VT + rl] = y[2];
            }
        }
        BAR_LGKM();
        // transpose out: per row, 3 coalesced dword NT stores of 64 cols each
        {
            int wv = t >> 6;
            const bool full = (ntile * 192 + 192 <= N3);
            for (int rr = wv; rr < 32; rr += 4) {
                size_t ob = (size_t)(b0 + q * 32 + rr) * N3 + (size_t)ntile * 192;
                if (full) {
                    #pragma unroll
                    for (int e = 0; e < 3; ++e) {
                        int col = e * 64 + lane;
                        __builtin_nontemporal_store(vtT[col * S_VT + rr], &out[ob + col]);
                    }
                } else {
                    #pragma unroll
                    for (int e = 0; e < 3; ++e) {
                        int col = e * 64 + lane;
                        if (ntile * 192 + col < N3)
                            __builtin_nontemporal_store(vtT[col * S_VT + rr], &out[ob + col]);
                    }
                }
            }
        }
    }
}

extern "C" void kernel_launch(void* const* d_in, const int* in_sizes, int n_in,
                              void* d_out, int out_size, void* d_ws, size_t ws_size,
                              hipStream_t stream) {
    const float* shp  = (const float*)d_in[0];
    const float* expn = (const float*)d_in[1];
    const float* neck = (const float*)d_in[2];
    const float* jaw  = (const float*)d_in[3];
    const float* eye  = (const float*)d_in[4];
    const float* vt   = (const float*)d_in[5];
    const float* sdir = (const float*)d_in[6];
    const float* pdir = (const float*)d_in[7];
    const float* jreg = (const float*)d_in[8];
    const float* lbsw = (const float*)d_in[9];
    char* ws  = (char*)d_ws;
    float* out = (float*)d_out;

    hipMemsetAsync(ws + WS_JD_B, 0, 2272 * 4, stream);
    k_prep <<<GP_J + GP_S + GP_P, 256, 0, stream>>>(jreg, sdir, vt, pdir, ws);
    k_batch<<<32, 64, 0, stream>>>(shp, expn, neck, jaw, eye, ws);
    k_mega <<<dim3(32, NTIL), 256, 0, stream>>>(ws, vt, lbsw, out);
}

// Round 4
// 247.614 us; speedup vs baseline: 1.4363x; 1.0318x over previous
//
#include <hip/hip_runtime.h>
#include <hip/hip_bf16.h>
#include <math.h>

#define NV   5023
#define N3   15069
#define NB   2048
#define NTIL 79            // ceil(N3/192) column tiles
#define NPAD (NTIL*192)    // 15168 padded B rows

// ---- workspace byte offsets ----
#define WS_JD_B   0          // 2272 floats
#define WS_ATR_B  9216       // 2048*60*4  = 491520
#define WS_AB_B   795648     // 2048*192*2 = 786432 (bf16 A)
#define WS_BB_B   1582080    // 15168*192*2 = 5824512 (bf16 B, n-major, padded)

// k_prep block ranges
#define GP_J 126             // jdirs slices
#define GP_S 1067            // sdirs->B cols 0..143 (NPAD*18 int4 / 256)
#define GP_P 237             // pose cols 144..191 (NPAD/64)

typedef __attribute__((ext_vector_type(8))) short short8;
typedef __attribute__((ext_vector_type(4))) float floatx4;

static __device__ __forceinline__ unsigned short f2bf(float x) {
    union { __hip_bfloat16 h; unsigned short s; } u;
    u.h = __float2bfloat16(x);
    return u.s;
}
static __device__ __forceinline__ unsigned int pk2(float a, float b) {
    return (unsigned int)f2bf(a) | ((unsigned int)f2bf(b) << 16);
}

// lgkmcnt-only barrier: cross-thread LDS ordering without draining the
// vmem store queue -- stores stay in flight across phases.
#define BAR_LGKM() do { \
    asm volatile("s_waitcnt lgkmcnt(0)" ::: "memory"); \
    __builtin_amdgcn_s_barrier(); \
    asm volatile("" ::: "memory"); \
} while (0)

// ---------------- fused prep: jdirs | B cols 0..143 | B cols 144..191 ----------------
__global__ void k_prep(const float* __restrict__ Jreg,   // [5][NV]
                       const float* __restrict__ sdirs,  // [NV][450] == [N3][150]
                       const float* __restrict__ vt,     // [NV][3]
                       const float* __restrict__ pdirs,  // [36][N3]
                       char* __restrict__ ws) {
    __shared__ float JregL[200];      // jdirs: 5 joints x 40 verts
    __shared__ float PL[36][65];      // pose transpose staging (+pad)
    const int t = threadIdx.x;

    if (blockIdx.x < GP_J) {
        // ---- Jdirs: 126 slices x 40 verts, Jreg staged in LDS ----
        int slice = blockIdx.x;
        int start = slice * 40;
        int end   = min(start + 40, NV);
        if (t < 200) {
            int j = t / 40, vl = t % 40;
            int v = start + vl;
            JregL[t] = (v < NV) ? Jreg[j * NV + v] : 0.f;
        }
        __syncthreads();
        int s0 = t, s1 = t + 256;
        float a0[5] = {0,0,0,0,0}, a1[5] = {0,0,0,0,0};
        #pragma unroll 2
        for (int v = start; v < end; ++v) {
            int vl = v - start;
            float x0 = (s0 < 450) ? sdirs[(size_t)v * 450 + s0]
                     : (s0 < 453 ? vt[v * 3 + (s0 - 450)] : 0.f);
            float x1 = (s1 < 450) ? sdirs[(size_t)v * 450 + s1]
                     : (s1 < 453 ? vt[v * 3 + (s1 - 450)] : 0.f);
            #pragma unroll
            for (int j = 0; j < 5; ++j) {
                float w = JregL[j * 40 + vl];
                a0[j] += w * x0; a1[j] += w * x1;
            }
        }
        float* Jd = (float*)(ws + WS_JD_B);
        #pragma unroll
        for (int j = 0; j < 5; ++j) {
            if (s0 < 453) atomicAdd(&Jd[j * 453 + s0], a0[j]);
            if (s1 < 453) atomicAdd(&Jd[j * 453 + s1], a1[j]);
        }
    } else if (blockIdx.x < GP_J + GP_S) {
        // ---- B cols 0..143: branch-free, aligned float2 reads, int4 writes ----
        int idx = (blockIdx.x - GP_J) * 256 + t;
        if (idx < NPAD * 18) {
            int n = idx / 18, g = idx % 18;
            __hip_bfloat16* dst = (__hip_bfloat16*)(ws + WS_BB_B) + (size_t)n * 192 + g * 8;
            if (n < N3) {
                const float* src = sdirs + (size_t)n * 150 + g * 8;   // 8B-aligned
                float2 p0 = *(const float2*)(src);
                float2 p1 = *(const float2*)(src + 2);
                float2 p2 = *(const float2*)(src + 4);
                float2 p3 = *(const float2*)(src + 6);
                unsigned int w[4] = { pk2(p0.x, p0.y), pk2(p1.x, p1.y),
                                      pk2(p2.x, p2.y), pk2(p3.x, p3.y) };
                *(int4*)dst = *(int4*)w;
            } else {
                int4 z = {0, 0, 0, 0};
                *(int4*)dst = z;
            }
        }
    } else {
        // ---- B cols 144..191: pdirs transposed via LDS (coalesced both sides) ----
        int pb = blockIdx.x - (GP_J + GP_S);
        int n0 = pb * 64;
        #pragma unroll
        for (int j = 0; j < 9; ++j) {
            int flat = j * 256 + t;          // < 2304 = 36*64
            int k = flat >> 6, i = flat & 63;
            int n = n0 + i;
            PL[k][i] = (n < N3) ? pdirs[(size_t)k * N3 + n] : 0.f;
        }
        __syncthreads();
        #pragma unroll
        for (int j = 0; j < 2; ++j) {
            int idx2 = j * 256 + t;
            if (idx2 < 384) {                // 64 rows x 6 int4
                int r = idx2 / 6, g = idx2 % 6;
                int n = n0 + r;
                int k0 = 144 + g * 8;
                __hip_bfloat16 val[8];
                #pragma unroll
                for (int e = 0; e < 8; ++e) {
                    int k = k0 + e;
                    float v = 0.f;
                    if (k < 150)      v = (n < N3) ? sdirs[(size_t)n * 150 + k] : 0.f;
                    else if (k < 186) v = PL[k - 150][r];
                    val[e] = __float2bfloat16(v);
                }
                *(int4*)((__hip_bfloat16*)(ws + WS_BB_B) + (size_t)n * 192 + k0) = *(int4*)val;
            }
        }
    }
}

// ---------------- rodrigues helper (inlined, static indexing) ----------------
static __device__ __forceinline__ void rodr3(float rx, float ry, float rz, float* R) {
    float ax = rx + 1e-8f, ay = ry + 1e-8f, az = rz + 1e-8f;
    float angle = sqrtf(ax*ax + ay*ay + az*az);
    float inv = 1.f / angle;
    float ux = rx * inv, uy = ry * inv, uz = rz * inv;
    float c = cosf(angle), s = sinf(angle);
    float K[9] = {0.f, -uz, uy,  uz, 0.f, -ux,  -uy, ux, 0.f};
    float KK[9];
    #pragma unroll
    for (int r = 0; r < 3; ++r)
        #pragma unroll
        for (int cc = 0; cc < 3; ++cc) {
            float a = 0.f;
            #pragma unroll
            for (int m = 0; m < 3; ++m) a += K[r*3+m] * K[m*3+cc];
            KK[r*3+cc] = a;
        }
    #pragma unroll
    for (int e = 0; e < 9; ++e) R[e] = s * K[e] + (1.f - c) * KK[e];
    R[0] += 1.f; R[4] += 1.f; R[8] += 1.f;
}

// ---------------- per-batch: J GEMV, rodrigues, chain -> Atr; writes bf16 A row directly ----------------
// Joint 0 pose is zero => R0 = I: A_0 = [I|0], G1 = [R1|J1], Gk = [R1*Rk | R1*(Jk-J1)+J1].
__global__ void k_batch(const float* __restrict__ shp,
                        const float* __restrict__ expn,
                        const float* __restrict__ neck,
                        const float* __restrict__ jaw,
                        const float* __restrict__ eye,
                        char* __restrict__ ws) {
    __shared__ float JdL[2265];
    {
        const float* Jd = (const float*)(ws + WS_JD_B);
        for (int i = threadIdx.x; i < 2265; i += 64) JdL[i] = Jd[i];
    }
    __syncthreads();
    int b = blockIdx.x * 64 + threadIdx.x;
    float* Atr = (float*)(ws + WS_ATR_B) + (size_t)b * 60;
    unsigned int* A32 = (unsigned int*)((char*)ws + WS_AB_B + (size_t)b * 384);

    float J[15];
    #pragma unroll
    for (int jk = 0; jk < 15; ++jk) J[jk] = JdL[(jk / 3) * 453 + 450 + (jk % 3)];

    // shape betas: 25 vectorized float4 loads (row = 400 B, 16B-aligned)
    for (int l4 = 0; l4 < 25; ++l4) {
        float4 be = *(const float4*)(shp + (size_t)b * 100 + l4 * 4);
        A32[2*l4]     = pk2(be.x, be.y);
        A32[2*l4 + 1] = pk2(be.z, be.w);
        float bev[4] = {be.x, be.y, be.z, be.w};
        #pragma unroll
        for (int e = 0; e < 4; ++e) {
            int l = l4 * 4 + e;
            #pragma unroll
            for (int jj = 0; jj < 5; ++jj)
                #pragma unroll
                for (int kk = 0; kk < 3; ++kk)
                    J[jj * 3 + kk] += JdL[jj * 453 + kk * 150 + l] * bev[e];
        }
    }
    // expression betas: 25 float2 loads (row = 200 B, 8B-aligned)
    for (int l2 = 0; l2 < 25; ++l2) {
        float2 be = *(const float2*)(expn + (size_t)b * 50 + l2 * 2);
        A32[50 + l2] = pk2(be.x, be.y);
        float bev[2] = {be.x, be.y};
        #pragma unroll
        for (int e = 0; e < 2; ++e) {
            int l = 100 + l2 * 2 + e;
            #pragma unroll
            for (int jj = 0; jj < 5; ++jj)
                #pragma unroll
                for (int kk = 0; kk < 3; ++kk)
                    J[jj * 3 + kk] += JdL[jj * 453 + kk * 150 + l] * bev[e];
        }
    }

    // rotations for posed joints 1..4 (neck, jaw, eyeL, eyeR)
    float R[4][9];
    rodr3(neck[b*3], neck[b*3+1], neck[b*3+2], R[0]);
    rodr3(jaw[b*3],  jaw[b*3+1],  jaw[b*3+2],  R[1]);
    rodr3(eye[b*6],  eye[b*6+1],  eye[b*6+2],  R[2]);
    rodr3(eye[b*6+3], eye[b*6+4], eye[b*6+5],  R[3]);

    // pose_feature -> bf16 A cols 150..185 directly (pf = R - I)
    #pragma unroll
    for (int i = 0; i < 18; ++i) {
        int x0 = 2*i, x1 = 2*i + 1;
        float p0 = R[x0/9][x0%9] - (((x0%9) % 4) == 0 ? 1.f : 0.f);
        float p1 = R[x1/9][x1%9] - (((x1%9) % 4) == 0 ? 1.f : 0.f);
        A32[75 + i] = pk2(p0, p1);
    }
    A32[93] = 0u; A32[94] = 0u; A32[95] = 0u;

    // joint 0: A = [I | 0]
    Atr[0]=1.f; Atr[1]=0.f; Atr[2]=0.f;  Atr[3]=0.f;
    Atr[4]=0.f; Atr[5]=1.f; Atr[6]=0.f;  Atr[7]=0.f;
    Atr[8]=0.f; Atr[9]=0.f; Atr[10]=1.f; Atr[11]=0.f;
    // joint 1 (neck): A = [R1 | J1 - R1*J1]
    #pragma unroll
    for (int r = 0; r < 3; ++r) {
        float d = R[0][r*3+0]*J[3] + R[0][r*3+1]*J[4] + R[0][r*3+2]*J[5];
        Atr[12 + r*4 + 0] = R[0][r*3+0];
        Atr[12 + r*4 + 1] = R[0][r*3+1];
        Atr[12 + r*4 + 2] = R[0][r*3+2];
        Atr[12 + r*4 + 3] = J[3+r] - d;
    }
    // joints 2..4 (parent = 1): G = [R1*Rk | R1*(Jk-J1)+J1], A col3 = t - G*Jk
    #pragma unroll
    for (int kk = 1; kk < 4; ++kk) {
        int jj = kk + 1;
        float rel[3];
        #pragma unroll
        for (int r = 0; r < 3; ++r) rel[r] = J[jj*3+r] - J[3+r];
        float Gr[9], tv[3];
        #pragma unroll
        for (int r = 0; r < 3; ++r) {
            #pragma unroll
            for (int cc = 0; cc < 3; ++cc) {
                float a = 0.f;
                #pragma unroll
                for (int m = 0; m < 3; ++m) a += R[0][r*3+m] * R[kk][m*3+cc];
                Gr[r*3+cc] = a;
            }
            tv[r] = R[0][r*3+0]*rel[0] + R[0][r*3+1]*rel[1] + R[0][r*3+2]*rel[2] + J[3+r];
        }
        #pragma unroll
        for (int r = 0; r < 3; ++r) {
            float d = Gr[r*3+0]*J[jj*3+0] + Gr[r*3+1]*J[jj*3+1] + Gr[r*3+2]*J[jj*3+2];
            Atr[jj*12 + r*4 + 0] = Gr[r*3+0];
            Atr[jj*12 + r*4 + 1] = Gr[r*3+1];
            Atr[jj*12 + r*4 + 2] = Gr[r*3+2];
            Atr[jj*12 + r*4 + 3] = tv[r] - d;
        }
    }
}

// ---------------- mega: bf16 MFMA GEMM + fused LBS epilogue ----------------
// M=64 batch x N=192 cols per block, K=192 (3 chunks of 64). 4 waves split over columns.
// Grid: x = batch tile (32), y = ntile (79) -> consecutive blocks share the B tile.
// Epilogue: Atr staged via registers (q1 loads issued during q0) so no global LOAD
// follows a store inside the loop -> no vmcnt entanglement. Cached (non-NT) output
// stores this round: traffic shape is clean (full 128B lines, disjoint rows per
// block), testing whether the NT path's ~1.5 TB/s was the store-side ceiling.
#define A_OFF  0          // 64 * 136 = 8704
#define B_OFF  8704       // 192 * 136 = 26112 -> 34816
#define S_VT   33         // vtT word stride
#define S_AT   61         // atrS word stride (61 coprime 32 -> conflict-free)
#define VT_T_OFF 0        // 192*33*4 = 25344
#define ATR_OFF  25344    // 32*61*4 = 7808 -> 33152
#define VTQ_OFF  33152    // 192*4 = 768 -> 33920
#define LBS_OFF  33920    // 320*4 = 1280 -> 35200
#define SMEM_BYTES 35200

__global__ __launch_bounds__(256, 3) void k_mega(
        const char* __restrict__ ws,
        const float* __restrict__ vt,     // [N3]
        const float* __restrict__ lbsw,   // [NV][5]
        float* __restrict__ out) {
    __shared__ __align__(16) unsigned char smem[SMEM_BYTES];
    const unsigned char* AbG = (const unsigned char*)ws + WS_AB_B;
    const unsigned char* BbG = (const unsigned char*)ws + WS_BB_B;
    const float* AtrG = (const float*)(ws + WS_ATR_B);

    const int ntile = blockIdx.y;          // 0..78
    const int b0    = blockIdx.x * 64;     // 32 tiles
    const int t     = threadIdx.x;
    const int lane  = t & 63;
    const int wn    = t >> 6;              // wave: column quarter
    const int l15 = lane & 15, quad = lane >> 4;

    floatx4 acc[4][3];
    #pragma unroll
    for (int f = 0; f < 4; ++f)
        #pragma unroll
        for (int g = 0; g < 3; ++g) {
            floatx4 z = {0.f, 0.f, 0.f, 0.f};
            acc[f][g] = z;
        }

    for (int chunk = 0; chunk < 3; ++chunk) {
        __syncthreads();
        // A: 64 rows x 128 B
        #pragma unroll
        for (int i = 0; i < 2; ++i) {
            int flat = i * 256 + t;
            int row = flat >> 3, piece = flat & 7;
            *(float4*)(smem + A_OFF + row * 136 + piece * 16) =
                *(const float4*)(AbG + (size_t)(b0 + row) * 384 + chunk * 128 + piece * 16);
        }
        // B: 192 rows x 128 B
        #pragma unroll
        for (int i = 0; i < 6; ++i) {
            int flat = i * 256 + t;
            int row = flat >> 3, piece = flat & 7;
            *(float4*)(smem + B_OFF + row * 136 + piece * 16) =
                *(const float4*)(BbG + (size_t)(ntile * 192 + row) * 384 + chunk * 128 + piece * 16);
        }
        __syncthreads();
        #pragma unroll
        for (int ks = 0; ks < 2; ++ks) {
            short8 af[4];
            #pragma unroll
            for (int f = 0; f < 4; ++f)
                af[f] = *(const short8*)(smem + A_OFF + (f * 16 + l15) * 136 + ks * 64 + quad * 16);
            #pragma unroll
            for (int g = 0; g < 3; ++g) {
                short8 bf = *(const short8*)(smem + B_OFF + (wn * 48 + g * 16 + l15) * 136 + ks * 64 + quad * 16);
                #pragma unroll
                for (int f = 0; f < 4; ++f)
                    acc[f][g] = __builtin_amdgcn_mfma_f32_16x16x32_bf16(af[f], bf, acc[f][g], 0, 0, 0);
            }
        }
    }
    __syncthreads();

    float* vtT  = (float*)(smem + VT_T_OFF);   // [192 cols][33]
    float* atrS = (float*)(smem + ATR_OFF);    // [32][61]
    float* vtQ  = (float*)(smem + VTQ_OFF);    // [192]
    float* lbsS = (float*)(smem + LBS_OFF);    // [64][5]

    // stage per-vertex constants once (after GEMM sync; ordered by next barrier)
    if (t < 192) { int n = ntile * 192 + t; vtQ[t] = (n < N3) ? vt[n] : 0.f; }
    for (int i = t; i < 320; i += 256) {
        int v = ntile * 64 + i / 5;
        lbsS[i] = (v < NV) ? lbsw[(size_t)v * 5 + (i % 5)] : 0.f;
    }
    // preload quarter-0 Atr into registers
    float arA[8], arB[8];
    #pragma unroll
    for (int u = 0; u < 8; ++u) {
        int i = u * 256 + t;
        arA[u] = (i < 1920) ? AtrG[(size_t)b0 * 60 + i] : 0.f;
    }

    // q = 0 and q = 1, written explicitly so all reg-array indexing is static
    #define EPI_PHASE(QQ, ARCUR, PRELOAD_NEXT)                                          \
    {                                                                                   \
        BAR_LGKM();                                                                     \
        /* dump acc rows [QQ*32, QQ*32+32) -> vtT[col][rl] */                           \
        _Pragma("unroll")                                                               \
        for (int ff2 = 0; ff2 < 2; ++ff2) {                                             \
            int f = QQ * 2 + ff2;                                                       \
            _Pragma("unroll")                                                           \
            for (int g = 0; g < 3; ++g) {                                               \
                int col = wn * 48 + g * 16 + l15;                                       \
                int rl  = ff2 * 16 + quad * 4;                                          \
                _Pragma("unroll")                                                       \
                for (int r = 0; r < 4; ++r)                                             \
                    vtT[col * S_VT + rl + r] = acc[f][g][r];                            \
            }                                                                           \
        }                                                                               \
        /* Atr -> LDS from registers */                                                 \
        _Pragma("unroll")                                                               \
        for (int u = 0; u < 8; ++u) {                                                   \
            int i = u * 256 + t;                                                        \
            if (i < 1920) {                                                             \
                int rw = i / 60, cw = i - rw * 60;                                      \
                atrS[rw * S_AT + cw] = ARCUR[u];                                        \
            }                                                                           \
        }                                                                               \
        PRELOAD_NEXT                                                                    \
        BAR_LGKM();                                                                     \
        /* LBS: rl = t&31, vgrp = t>>5 (8 verts each) */                                \
        {                                                                               \
            int rl = t & 31;                                                            \
            int vgrp = t >> 5;                                                          \
            float ar[60];                                                               \
            _Pragma("unroll")                                                           \
            for (int i = 0; i < 60; ++i) ar[i] = atrS[rl * S_AT + i];                   \
            _Pragma("unroll")                                                           \
            for (int vv = 0; vv < 8; ++vv) {                                            \
                int vloc = vgrp * 8 + vv;                                               \
                int c0 = vloc * 3;                                                      \
                float w0 = lbsS[vloc*5+0], w1 = lbsS[vloc*5+1], w2 = lbsS[vloc*5+2],    \
                      w3 = lbsS[vloc*5+3], w4 = lbsS[vloc*5+4];                         \
                float px = vtT[(c0+0) * S_VT + rl] + vtQ[c0+0];                         \
                float py = vtT[(c0+1) * S_VT + rl] + vtQ[c0+1];                         \
                float pz = vtT[(c0+2) * S_VT + rl] + vtQ[c0+2];                         \
                float y[3];                                                             \
                _Pragma("unroll")                                                       \
                for (int r = 0; r < 3; ++r) {                                           \
                    float t0 = w0*ar[ 0+r*4+0] + w1*ar[12+r*4+0] + w2*ar[24+r*4+0]      \
                             + w3*ar[36+r*4+0] + w4*ar[48+r*4+0];                       \
                    float t1 = w0*ar[ 0+r*4+1] + w1*ar[12+r*4+1] + w2*ar[24+r*4+1]      \
                             + w3*ar[36+r*4+1] + w4*ar[48+r*4+1];                       \
                    float t2 = w0*ar[ 0+r*4+2] + w1*ar[12+r*4+2] + w2*ar[24+r*4+2]      \
                             + w3*ar[36+r*4+2] + w4*ar[48+r*4+2];                       \
                    float t3 = w0*ar[ 0+r*4+3] + w1*ar[12+r*4+3] + w2*ar[24+r*4+3]      \
                             + w3*ar[36+r*4+3] + w4*ar[48+r*4+3];                       \
                    y[r] = t0*px + t1*py + t2*pz + t3;                                  \
                }                                                                       \
                vtT[(c0+0) * S_VT + rl] = y[0];                                         \
                vtT[(c0+1) * S_VT + rl] = y[1];                                         \
                vtT[(c0+2) * S_VT + rl] = y[2];                                         \
            }                                                                           \
        }                                                                               \
        BAR_LGKM();                                                                     \
        /* transpose out: per row, 3 coalesced dword stores of 64 cols each */          \
        {                                                                               \
            int wv = t >> 6;                                                            \
            const bool full = (ntile * 192 + 192 <= N3);                                \
            for (int rr = wv; rr < 32; rr += 4) {                                       \
                size_t ob = (size_t)(b0 + QQ * 32 + rr) * N3 + (size_t)ntile * 192;     \
                if (full) {                                                             \
                    _Pragma("unroll")                                                   \
                    for (int e = 0; e < 3; ++e) {                                       \
                        int col = e * 64 + lane;                                        \
                        out[ob + col] = vtT[col * S_VT + rr];                           \
                    }                                                                   \
                } else {                                                                \
                    _Pragma("unroll")                                                   \
                    for (int e = 0; e < 3; ++e) {                                       \
                        int col = e * 64 + lane;                                        \
                        if (ntile * 192 + col < N3)                                     \
                            out[ob + col] = vtT[col * S_VT + rr];                       \
                    }                                                                   \
                }                                                                       \
            }                                                                           \
        }                                                                               \
    }

    EPI_PHASE(0, arA,
        { _Pragma("unroll")
          for (int u = 0; u < 8; ++u) {
              int i = u * 256 + t;
              arB[u] = (i < 1920) ? AtrG[(size_t)(b0 + 32) * 60 + i] : 0.f;
          } } )
    EPI_PHASE(1, arB, { } )
    #undef EPI_PHASE
}

extern "C" void kernel_launch(void* const* d_in, const int* in_sizes, int n_in,
                              void* d_out, int out_size, void* d_ws, size_t ws_size,
                              hipStream_t stream) {
    const float* shp  = (const float*)d_in[0];
    const float* expn = (const float*)d_in[1];
    const float* neck = (const float*)d_in[2];
    const float* jaw  = (const float*)d_in[3];
    const float* eye  = (const float*)d_in[4];
    const float* vt   = (const float*)d_in[5];
    const float* sdir = (const float*)d_in[6];
    const float* pdir = (const float*)d_in[7];
    const float* jreg = (const float*)d_in[8];
    const float* lbsw = (const float*)d_in[9];
    char* ws  = (char*)d_ws;
    float* out = (float*)d_out;

    hipMemsetAsync(ws + WS_JD_B, 0, 2272 * 4, stream);
    k_prep <<<GP_J + GP_S + GP_P, 256, 0, stream>>>(jreg, sdir, vt, pdir, ws);
    k_batch<<<32, 64, 0, stream>>>(shp, expn, neck, jaw, eye, ws);
    k_mega <<<dim3(32, NTIL), 256, 0, stream>>>(ws, vt, lbsw, out);
}

// Round 5
// 247.263 us; speedup vs baseline: 1.4384x; 1.0014x over previous
//
#include <hip/hip_runtime.h>
#include <hip/hip_bf16.h>
#include <math.h>

#define NV   5023
#define N3   15069
#define NB   2048
#define NTIL 79            // ceil(N3/192) column tiles
#define NPAD (NTIL*192)    // 15168 padded B rows

// ---- workspace byte offsets ----
#define WS_JD_B   0          // 2272 floats
#define WS_ATR_B  9216       // 2048*60*4  = 491520
#define WS_AB_B   795648     // 2048*192*2 = 786432 (bf16 A)
#define WS_BB_B   1582080    // 15168*192*2 = 5824512 (bf16 B, n-major, padded)

// k_prep block ranges
#define GP_J 126             // jdirs slices
#define GP_S 1067            // sdirs->B cols 0..143 (NPAD*18 int4 / 256)
#define GP_P 237             // pose cols 144..191 (NPAD/64)

typedef __attribute__((ext_vector_type(8))) short short8;
typedef __attribute__((ext_vector_type(4))) float floatx4;

static __device__ __forceinline__ unsigned short f2bf(float x) {
    union { __hip_bfloat16 h; unsigned short s; } u;
    u.h = __float2bfloat16(x);
    return u.s;
}
static __device__ __forceinline__ unsigned int pk2(float a, float b) {
    return (unsigned int)f2bf(a) | ((unsigned int)f2bf(b) << 16);
}

// lgkmcnt-only barrier: cross-thread LDS ordering without draining the
// vmem store queue -- stores stay in flight across phases.
#define BAR_LGKM() do { \
    asm volatile("s_waitcnt lgkmcnt(0)" ::: "memory"); \
    __builtin_amdgcn_s_barrier(); \
    asm volatile("" ::: "memory"); \
} while (0)

// ---------------- fused prep: jdirs | B cols 0..143 | B cols 144..191 ----------------
__global__ void k_prep(const float* __restrict__ Jreg,   // [5][NV]
                       const float* __restrict__ sdirs,  // [NV][450] == [N3][150]
                       const float* __restrict__ vt,     // [NV][3]
                       const float* __restrict__ pdirs,  // [36][N3]
                       char* __restrict__ ws) {
    __shared__ float JregL[200];      // jdirs: 5 joints x 40 verts
    __shared__ float PL[36][65];      // pose transpose staging (+pad)
    const int t = threadIdx.x;

    if (blockIdx.x < GP_J) {
        // ---- Jdirs: 126 slices x 40 verts, Jreg staged in LDS ----
        int slice = blockIdx.x;
        int start = slice * 40;
        int end   = min(start + 40, NV);
        if (t < 200) {
            int j = t / 40, vl = t % 40;
            int v = start + vl;
            JregL[t] = (v < NV) ? Jreg[j * NV + v] : 0.f;
        }
        __syncthreads();
        int s0 = t, s1 = t + 256;
        float a0[5] = {0,0,0,0,0}, a1[5] = {0,0,0,0,0};
        #pragma unroll 2
        for (int v = start; v < end; ++v) {
            int vl = v - start;
            float x0 = (s0 < 450) ? sdirs[(size_t)v * 450 + s0]
                     : (s0 < 453 ? vt[v * 3 + (s0 - 450)] : 0.f);
            float x1 = (s1 < 450) ? sdirs[(size_t)v * 450 + s1]
                     : (s1 < 453 ? vt[v * 3 + (s1 - 450)] : 0.f);
            #pragma unroll
            for (int j = 0; j < 5; ++j) {
                float w = JregL[j * 40 + vl];
                a0[j] += w * x0; a1[j] += w * x1;
            }
        }
        float* Jd = (float*)(ws + WS_JD_B);
        #pragma unroll
        for (int j = 0; j < 5; ++j) {
            if (s0 < 453) atomicAdd(&Jd[j * 453 + s0], a0[j]);
            if (s1 < 453) atomicAdd(&Jd[j * 453 + s1], a1[j]);
        }
    } else if (blockIdx.x < GP_J + GP_S) {
        // ---- B cols 0..143: branch-free, aligned float2 reads, int4 writes ----
        int idx = (blockIdx.x - GP_J) * 256 + t;
        if (idx < NPAD * 18) {
            int n = idx / 18, g = idx % 18;
            __hip_bfloat16* dst = (__hip_bfloat16*)(ws + WS_BB_B) + (size_t)n * 192 + g * 8;
            if (n < N3) {
                const float* src = sdirs + (size_t)n * 150 + g * 8;   // 8B-aligned
                float2 p0 = *(const float2*)(src);
                float2 p1 = *(const float2*)(src + 2);
                float2 p2 = *(const float2*)(src + 4);
                float2 p3 = *(const float2*)(src + 6);
                unsigned int w[4] = { pk2(p0.x, p0.y), pk2(p1.x, p1.y),
                                      pk2(p2.x, p2.y), pk2(p3.x, p3.y) };
                *(int4*)dst = *(int4*)w;
            } else {
                int4 z = {0, 0, 0, 0};
                *(int4*)dst = z;
            }
        }
    } else {
        // ---- B cols 144..191: pdirs transposed via LDS (coalesced both sides) ----
        int pb = blockIdx.x - (GP_J + GP_S);
        int n0 = pb * 64;
        #pragma unroll
        for (int j = 0; j < 9; ++j) {
            int flat = j * 256 + t;          // < 2304 = 36*64
            int k = flat >> 6, i = flat & 63;
            int n = n0 + i;
            PL[k][i] = (n < N3) ? pdirs[(size_t)k * N3 + n] : 0.f;
        }
        __syncthreads();
        #pragma unroll
        for (int j = 0; j < 2; ++j) {
            int idx2 = j * 256 + t;
            if (idx2 < 384) {                // 64 rows x 6 int4
                int r = idx2 / 6, g = idx2 % 6;
                int n = n0 + r;
                int k0 = 144 + g * 8;
                __hip_bfloat16 val[8];
                #pragma unroll
                for (int e = 0; e < 8; ++e) {
                    int k = k0 + e;
                    float v = 0.f;
                    if (k < 150)      v = (n < N3) ? sdirs[(size_t)n * 150 + k] : 0.f;
                    else if (k < 186) v = PL[k - 150][r];
                    val[e] = __float2bfloat16(v);
                }
                *(int4*)((__hip_bfloat16*)(ws + WS_BB_B) + (size_t)n * 192 + k0) = *(int4*)val;
            }
        }
    }
}

// ---------------- rodrigues helper (inlined, static indexing) ----------------
static __device__ __forceinline__ void rodr3(float rx, float ry, float rz, float* R) {
    float ax = rx + 1e-8f, ay = ry + 1e-8f, az = rz + 1e-8f;
    float angle = sqrtf(ax*ax + ay*ay + az*az);
    float inv = 1.f / angle;
    float ux = rx * inv, uy = ry * inv, uz = rz * inv;
    float c = cosf(angle), s = sinf(angle);
    float K[9] = {0.f, -uz, uy,  uz, 0.f, -ux,  -uy, ux, 0.f};
    float KK[9];
    #pragma unroll
    for (int r = 0; r < 3; ++r)
        #pragma unroll
        for (int cc = 0; cc < 3; ++cc) {
            float a = 0.f;
            #pragma unroll
            for (int m = 0; m < 3; ++m) a += K[r*3+m] * K[m*3+cc];
            KK[r*3+cc] = a;
        }
    #pragma unroll
    for (int e = 0; e < 9; ++e) R[e] = s * K[e] + (1.f - c) * KK[e];
    R[0] += 1.f; R[4] += 1.f; R[8] += 1.f;
}

// ---------------- per-batch: coalesced LDS-staged version ----------------
// 32 blocks x 256 threads; each block handles 64 batch elements.
// Phase 1: coalesced staging of shp/exp tiles + Jd into LDS (padded strides,
//          all coprime with 32 banks). Phase 2: J-GEMV split 4-ways across
//          waves (seg = wave id), LDS reduction. Phase 3 (wave 0): rodrigues +
//          chain -> Atr, pf -> LDS. Phase 4: all threads write bf16 A rows
//          coalesced from LDS.
#define KBS 0        // shp staged [64][101]
#define KBE 6464     // exp staged [64][51]
#define KBJ 9728     // Jd [2265]
#define KBR 11993    // reduction [4][64][17]
#define KBP 16345    // pf [64][37]
#define KBT 18713    // total floats (74852 B)

__global__ __launch_bounds__(256) void k_batch(
        const float* __restrict__ shp,
        const float* __restrict__ expn,
        const float* __restrict__ neck,
        const float* __restrict__ jaw,
        const float* __restrict__ eye,
        char* __restrict__ ws) {
    __shared__ float L[KBT];
    const int t  = threadIdx.x;
    const int b0 = blockIdx.x * 64;

    {
        const float* Jd = (const float*)(ws + WS_JD_B);
        for (int i = t; i < 6400; i += 256) { int r = i / 100, c = i - r * 100; L[KBS + r*101 + c] = shp[(size_t)b0*100 + i]; }
        for (int i = t; i < 3200; i += 256) { int r = i / 50,  c = i - r * 50;  L[KBE + r*51  + c] = expn[(size_t)b0*50 + i]; }
        for (int i = t; i < 2265; i += 256) L[KBJ + i] = Jd[i];
    }
    __syncthreads();

    const int br = t & 63, seg = t >> 6;   // seg uniform per wave
    {
        float Jp[15];
        #pragma unroll
        for (int u = 0; u < 15; ++u) Jp[u] = 0.f;
        int l0 = seg * 38, l1 = (seg == 3) ? 150 : (l0 + 38);
        for (int l = l0; l < l1; ++l) {
            float be = (l < 100) ? L[KBS + br*101 + l] : L[KBE + br*51 + (l - 100)];
            #pragma unroll
            for (int jj = 0; jj < 5; ++jj)
                #pragma unroll
                for (int kk = 0; kk < 3; ++kk)
                    Jp[jj*3 + kk] += L[KBJ + jj*453 + kk*150 + l] * be;
        }
        #pragma unroll
        for (int u = 0; u < 15; ++u) L[KBR + (seg*64 + br)*17 + u] = Jp[u];
    }
    __syncthreads();

    if (t < 64) {
        int b = b0 + t;
        float J[15];
        #pragma unroll
        for (int jk = 0; jk < 15; ++jk) {
            float s = L[KBJ + (jk/3)*453 + 450 + (jk%3)];
            #pragma unroll
            for (int sg = 0; sg < 4; ++sg) s += L[KBR + (sg*64 + t)*17 + jk];
            J[jk] = s;
        }

        float R[4][9];
        rodr3(neck[b*3], neck[b*3+1], neck[b*3+2], R[0]);
        rodr3(jaw[b*3],  jaw[b*3+1],  jaw[b*3+2],  R[1]);
        rodr3(eye[b*6],  eye[b*6+1],  eye[b*6+2],  R[2]);
        rodr3(eye[b*6+3], eye[b*6+4], eye[b*6+5],  R[3]);

        // pf = R - I -> LDS for the A-write phase
        #pragma unroll
        for (int kk2 = 0; kk2 < 4; ++kk2)
            #pragma unroll
            for (int e = 0; e < 9; ++e)
                L[KBP + t*37 + kk2*9 + e] = R[kk2][e] - ((e == 0 || e == 4 || e == 8) ? 1.f : 0.f);

        // chain -> Atr (joint0 = I; G1 = [R1|J1]; Gk = [R1*Rk | R1*(Jk-J1)+J1])
        float* Atr = (float*)(ws + WS_ATR_B) + (size_t)b * 60;
        Atr[0]=1.f; Atr[1]=0.f; Atr[2]=0.f;  Atr[3]=0.f;
        Atr[4]=0.f; Atr[5]=1.f; Atr[6]=0.f;  Atr[7]=0.f;
        Atr[8]=0.f; Atr[9]=0.f; Atr[10]=1.f; Atr[11]=0.f;
        #pragma unroll
        for (int r = 0; r < 3; ++r) {
            float d = R[0][r*3+0]*J[3] + R[0][r*3+1]*J[4] + R[0][r*3+2]*J[5];
            Atr[12 + r*4 + 0] = R[0][r*3+0];
            Atr[12 + r*4 + 1] = R[0][r*3+1];
            Atr[12 + r*4 + 2] = R[0][r*3+2];
            Atr[12 + r*4 + 3] = J[3+r] - d;
        }
        #pragma unroll
        for (int kk = 1; kk < 4; ++kk) {
            int jj = kk + 1;
            float rel[3];
            #pragma unroll
            for (int r = 0; r < 3; ++r) rel[r] = J[jj*3+r] - J[3+r];
            float Gr[9], tv[3];
            #pragma unroll
            for (int r = 0; r < 3; ++r) {
                #pragma unroll
                for (int cc = 0; cc < 3; ++cc) {
                    float a = 0.f;
                    #pragma unroll
                    for (int m = 0; m < 3; ++m) a += R[0][r*3+m] * R[kk][m*3+cc];
                    Gr[r*3+cc] = a;
                }
                tv[r] = R[0][r*3+0]*rel[0] + R[0][r*3+1]*rel[1] + R[0][r*3+2]*rel[2] + J[3+r];
            }
            #pragma unroll
            for (int r = 0; r < 3; ++r) {
                float d = Gr[r*3+0]*J[jj*3+0] + Gr[r*3+1]*J[jj*3+1] + Gr[r*3+2]*J[jj*3+2];
                Atr[jj*12 + r*4 + 0] = Gr[r*3+0];
                Atr[jj*12 + r*4 + 1] = Gr[r*3+1];
                Atr[jj*12 + r*4 + 2] = Gr[r*3+2];
                Atr[jj*12 + r*4 + 3] = tv[r] - d;
            }
        }
    }
    __syncthreads();

    // bf16 A rows [64][96 words], coalesced
    unsigned int* A32g = (unsigned int*)(ws + WS_AB_B);
    for (int i = t; i < 6144; i += 256) {
        int r = i / 96, w = i - r * 96;
        unsigned int val;
        if (w < 50)      val = pk2(L[KBS + r*101 + 2*w],     L[KBS + r*101 + 2*w + 1]);
        else if (w < 75) { int c = 2*(w-50); val = pk2(L[KBE + r*51 + c], L[KBE + r*51 + c + 1]); }
        else if (w < 93) { int c = 2*(w-75); val = pk2(L[KBP + r*37 + c], L[KBP + r*37 + c + 1]); }
        else             val = 0u;
        A32g[(size_t)(b0 + r)*96 + w] = val;
    }
}

// ---------------- mega: bf16 MFMA GEMM + fused LBS epilogue ----------------
// M=64 batch x N=192 cols per block, K=192 (3 chunks of 64). 4 waves split over columns.
// Grid: x = batch tile (32), y = ntile (79) -> consecutive blocks share the B tile.
// launch_bounds(256,4): 4 blocks/CU (LDS 35328*4 = 141 KB <= 160 KB; regs 120 <= 128)
// -> +33% resident waves for this latency-bound kernel.
#define A_OFF  0          // 64 * 136 = 8704
#define B_OFF  8704       // 192 * 136 = 26112 -> 34816
#define S_VT   33         // vtT word stride
#define S_AT   61         // atrS word stride (61 coprime 32 -> conflict-free)
#define VT_T_OFF 0        // 192*33*4 = 25344
#define ATR_OFF  25344    // 32*61*4 = 7808 -> 33152
#define VTQ_OFF  33152    // 192*4 = 768 -> 33920
#define LBS_OFF  33920    // 320*4 = 1280 -> 35200
#define SMEM_BYTES 35200

__global__ __launch_bounds__(256, 4) void k_mega(
        const char* __restrict__ ws,
        const float* __restrict__ vt,     // [N3]
        const float* __restrict__ lbsw,   // [NV][5]
        float* __restrict__ out) {
    __shared__ __align__(16) unsigned char smem[SMEM_BYTES];
    const unsigned char* AbG = (const unsigned char*)ws + WS_AB_B;
    const unsigned char* BbG = (const unsigned char*)ws + WS_BB_B;
    const float* AtrG = (const float*)(ws + WS_ATR_B);

    const int ntile = blockIdx.y;          // 0..78
    const int b0    = blockIdx.x * 64;     // 32 tiles
    const int t     = threadIdx.x;
    const int lane  = t & 63;
    const int wn    = t >> 6;              // wave: column quarter
    const int l15 = lane & 15, quad = lane >> 4;

    floatx4 acc[4][3];
    #pragma unroll
    for (int f = 0; f < 4; ++f)
        #pragma unroll
        for (int g = 0; g < 3; ++g) {
            floatx4 z = {0.f, 0.f, 0.f, 0.f};
            acc[f][g] = z;
        }

    for (int chunk = 0; chunk < 3; ++chunk) {
        __syncthreads();
        // A: 64 rows x 128 B
        #pragma unroll
        for (int i = 0; i < 2; ++i) {
            int flat = i * 256 + t;
            int row = flat >> 3, piece = flat & 7;
            *(float4*)(smem + A_OFF + row * 136 + piece * 16) =
                *(const float4*)(AbG + (size_t)(b0 + row) * 384 + chunk * 128 + piece * 16);
        }
        // B: 192 rows x 128 B
        #pragma unroll
        for (int i = 0; i < 6; ++i) {
            int flat = i * 256 + t;
            int row = flat >> 3, piece = flat & 7;
            *(float4*)(smem + B_OFF + row * 136 + piece * 16) =
                *(const float4*)(BbG + (size_t)(ntile * 192 + row) * 384 + chunk * 128 + piece * 16);
        }
        __syncthreads();
        #pragma unroll
        for (int ks = 0; ks < 2; ++ks) {
            short8 af[4];
            #pragma unroll
            for (int f = 0; f < 4; ++f)
                af[f] = *(const short8*)(smem + A_OFF + (f * 16 + l15) * 136 + ks * 64 + quad * 16);
            #pragma unroll
            for (int g = 0; g < 3; ++g) {
                short8 bf = *(const short8*)(smem + B_OFF + (wn * 48 + g * 16 + l15) * 136 + ks * 64 + quad * 16);
                #pragma unroll
                for (int f = 0; f < 4; ++f)
                    acc[f][g] = __builtin_amdgcn_mfma_f32_16x16x32_bf16(af[f], bf, acc[f][g], 0, 0, 0);
            }
        }
    }
    __syncthreads();

    float* vtT  = (float*)(smem + VT_T_OFF);   // [192 cols][33]
    float* atrS = (float*)(smem + ATR_OFF);    // [32][61]
    float* vtQ  = (float*)(smem + VTQ_OFF);    // [192]
    float* lbsS = (float*)(smem + LBS_OFF);    // [64][5]

    // stage per-vertex constants once (after GEMM sync; ordered by next barrier)
    if (t < 192) { int n = ntile * 192 + t; vtQ[t] = (n < N3) ? vt[n] : 0.f; }
    for (int i = t; i < 320; i += 256) {
        int v = ntile * 64 + i / 5;
        lbsS[i] = (v < NV) ? lbsw[(size_t)v * 5 + (i % 5)] : 0.f;
    }
    // preload quarter-0 Atr into registers
    float arA[8], arB[8];
    #pragma unroll
    for (int u = 0; u < 8; ++u) {
        int i = u * 256 + t;
        arA[u] = (i < 1920) ? AtrG[(size_t)b0 * 60 + i] : 0.f;
    }

    // q = 0 and q = 1, written explicitly so all reg-array indexing is static
    #define EPI_PHASE(QQ, ARCUR, PRELOAD_NEXT)                                          \
    {                                                                                   \
        BAR_LGKM();                                                                     \
        /* dump acc rows [QQ*32, QQ*32+32) -> vtT[col][rl] */                           \
        _Pragma("unroll")                                                               \
        for (int ff2 = 0; ff2 < 2; ++ff2) {                                             \
            int f = QQ * 2 + ff2;                                                       \
            _Pragma("unroll")                                                           \
            for (int g = 0; g < 3; ++g) {                                               \
                int col = wn * 48 + g * 16 + l15;                                       \
                int rl  = ff2 * 16 + quad * 4;                                          \
                _Pragma("unroll")                                                       \
                for (int r = 0; r < 4; ++r)                                             \
                    vtT[col * S_VT + rl + r] = acc[f][g][r];                            \
            }                                                                           \
        }                                                                               \
        /* Atr -> LDS from registers */                                                 \
        _Pragma("unroll")                                                               \
        for (int u = 0; u < 8; ++u) {                                                   \
            int i = u * 256 + t;                                                        \
            if (i < 1920) {                                                             \
                int rw = i / 60, cw = i - rw * 60;                                      \
                atrS[rw * S_AT + cw] = ARCUR[u];                                        \
            }                                                                           \
        }                                                                               \
        PRELOAD_NEXT                                                                    \
        BAR_LGKM();                                                                     \
        /* LBS: rl = t&31, vgrp = t>>5 (8 verts each) */                                \
        {                                                                               \
            int rl = t & 31;                                                            \
            int vgrp = t >> 5;                                                          \
            float ar[60];                                                               \
            _Pragma("unroll")                                                           \
            for (int i = 0; i < 60; ++i) ar[i] = atrS[rl * S_AT + i];                   \
            _Pragma("unroll")                                                           \
            for (int vv = 0; vv < 8; ++vv) {                                            \
                int vloc = vgrp * 8 + vv;                                               \
                int c0 = vloc * 3;                                                      \
                float w0 = lbsS[vloc*5+0], w1 = lbsS[vloc*5+1], w2 = lbsS[vloc*5+2],    \
                      w3 = lbsS[vloc*5+3], w4 = lbsS[vloc*5+4];                         \
                float px = vtT[(c0+0) * S_VT + rl] + vtQ[c0+0];                         \
                float py = vtT[(c0+1) * S_VT + rl] + vtQ[c0+1];                         \
                float pz = vtT[(c0+2) * S_VT + rl] + vtQ[c0+2];                         \
                float y[3];                                                             \
                _Pragma("unroll")                                                       \
                for (int r = 0; r < 3; ++r) {                                           \
                    float t0 = w0*ar[ 0+r*4+0] + w1*ar[12+r*4+0] + w2*ar[24+r*4+0]      \
                             + w3*ar[36+r*4+0] + w4*ar[48+r*4+0];                       \
                    float t1 = w0*ar[ 0+r*4+1] + w1*ar[12+r*4+1] + w2*ar[24+r*4+1]      \
                             + w3*ar[36+r*4+1] + w4*ar[48+r*4+1];                       \
                    float t2 = w0*ar[ 0+r*4+2] + w1*ar[12+r*4+2] + w2*ar[24+r*4+2]      \
                             + w3*ar[36+r*4+2] + w4*ar[48+r*4+2];                       \
                    float t3 = w0*ar[ 0+r*4+3] + w1*ar[12+r*4+3] + w2*ar[24+r*4+3]      \
                             + w3*ar[36+r*4+3] + w4*ar[48+r*4+3];                       \
                    y[r] = t0*px + t1*py + t2*pz + t3;                                  \
                }                                                                       \
                vtT[(c0+0) * S_VT + rl] = y[0];                                         \
                vtT[(c0+1) * S_VT + rl] = y[1];                                         \
                vtT[(c0+2) * S_VT + rl] = y[2];                                         \
            }                                                                           \
        }                                                                               \
        BAR_LGKM();                                                                     \
        /* transpose out: per row, 3 coalesced dword stores of 64 cols each */          \
        {                                                                               \
            int wv = t >> 6;                                                            \
            const bool full = (ntile * 192 + 192 <= N3);                                \
            for (int rr = wv; rr < 32; rr += 4) {                                       \
                size_t ob = (size_t)(b0 + QQ * 32 + rr) * N3 + (size_t)ntile * 192;     \
                if (full) {                                                             \
                    _Pragma("unroll")                                                   \
                    for (int e = 0; e < 3; ++e) {                                       \
                        int col = e * 64 + lane;                                        \
                        out[ob + col] = vtT[col * S_VT + rr];                           \
                    }                                                                   \
                } else {                                                                \
                    _Pragma("unroll")                                                   \
                    for (int e = 0; e < 3; ++e) {                                       \
                        int col = e * 64 + lane;                                        \
                        if (ntile * 192 + col < N3)                                     \
                            out[ob + col] = vtT[col * S_VT + rr];                       \
                    }                                                                   \
                }                                                                       \
            }                                                                           \
        }                                                                               \
    }

    EPI_PHASE(0, arA,
        { _Pragma("unroll")
          for (int u = 0; u < 8; ++u) {
              int i = u * 256 + t;
              arB[u] = (i < 1920) ? AtrG[(size_t)(b0 + 32) * 60 + i] : 0.f;
          } } )
    EPI_PHASE(1, arB, { } )
    #undef EPI_PHASE
}

extern "C" void kernel_launch(void* const* d_in, const int* in_sizes, int n_in,
                              void* d_out, int out_size, void* d_ws, size_t ws_size,
                              hipStream_t stream) {
    const float* shp  = (const float*)d_in[0];
    const float* expn = (const float*)d_in[1];
    const float* neck = (const float*)d_in[2];
    const float* jaw  = (const float*)d_in[3];
    const float* eye  = (const float*)d_in[4];
    const float* vt   = (const float*)d_in[5];
    const float* sdir = (const float*)d_in[6];
    const float* pdir = (const float*)d_in[7];
    const float* jreg = (const float*)d_in[8];
    const float* lbsw = (const float*)d_in[9];
    char* ws  = (char*)d_ws;
    float* out = (float*)d_out;

    hipMemsetAsync(ws + WS_JD_B, 0, 2272 * 4, stream);
    k_prep <<<GP_J + GP_S + GP_P, 256, 0, stream>>>(jreg, sdir, vt, pdir, ws);
    k_batch<<<32, 256, 0, stream>>>(shp, expn, neck, jaw, eye, ws);
    k_mega <<<dim3(32, NTIL), 256, 0, stream>>>(ws, vt, lbsw, out);
}